// Round 5
// baseline (532.814 us; speedup 1.0000x reference)
//
#include <hip/hip_runtime.h>
#include <stdint.h>

#define T_STEPS 512
#define BATCH   128
#define N_IN    256
#define N_H     1024
#define N_OUT   32

typedef __attribute__((ext_vector_type(2))) float f32x2;

// Workspace layout (needs 22,282,240 B; round-4 proved capacity):
//   pm    u32[65536][32]  @ 0          8,388,608  (main idx, pre-mult <<7)
//   pt    u16[65536][32]  @ 8388608    4,194,304  (tail idx, raw)
//   cnts  u32[65536]      @ 12582912     262,144
//   w_t   f32[256][1024]  @ 12845056   1,048,576
//   zmask u32[65536][32]  @ 13893632   8,388,608  (word = 32-col tile, bit j = h%32)

// ---------------- Kernel A: compact spike indices, 4 rows per block ----------------
// pm slots 0-15 = even list positions, 16-31 = odd, stored as byte offsets
// (idx<<7 for the 128 B tile-32 rows; sentinel 256<<7 = zeroed row 256).
// pt = raw u16 tail (slots 32-63). cnts[row] = active count.
__global__ __launch_bounds__(256) void k_prep(const float* __restrict__ spikes,
                                              uint32_t* __restrict__ pm,
                                              uint16_t* __restrict__ pt,
                                              uint32_t* __restrict__ cnts) {
    __shared__ uint16_t list[64];
    __shared__ uint32_t wcnt[4];
    const int tid = threadIdx.x;
    const int wave = tid >> 6, lane = tid & 63;
    for (int r = 0; r < 4; ++r) {
        const int row = blockIdx.x * 4 + r;        // t*BATCH + b
        float s = spikes[(size_t)row * N_IN + tid];
        bool act = s > 0.5f;                       // spikes are exactly 0.0/1.0
        unsigned long long m = __ballot(act);
        if (tid < 64) list[tid] = 256;             // sentinel
        if (lane == 0) wcnt[wave] = (uint32_t)__popcll(m);
        __syncthreads();
        uint32_t off = 0;
        for (int w = 0; w < wave; ++w) off += wcnt[w];
        uint32_t total = wcnt[0] + wcnt[1] + wcnt[2] + wcnt[3];
        if (act) {
            uint32_t pos = off + (uint32_t)__popcll(m & ((1ull << lane) - 1ull));
            if (pos < 64) list[pos] = (uint16_t)tid;   // ascending input index order
        }
        __syncthreads();
        if (tid < 32) {                        // main: u32 byte offsets (<<7)
            int h = tid >> 4, sl = tid & 15;
            pm[(uint32_t)row * 32 + tid] = ((uint32_t)list[2 * sl + h]) << 7;
        } else if (tid < 64) {                 // tail: raw u16
            int u = tid & 31;
            int h = u >> 4, sl = u & 15;
            pt[(uint32_t)row * 32 + u] = list[32 + 2 * sl + h];
        }
        if (tid == 0) cnts[row] = total < 64u ? total : 64u;
        __syncthreads();
    }
}

// ---------------- Kernel T: transpose w_h[h][i] -> w_t[i][h] ----------------
__global__ __launch_bounds__(256) void k_tr(const float* __restrict__ w_h,
                                            float* __restrict__ w_t) {
    int gid = blockIdx.x * 256 + threadIdx.x;   // 262144 elements
    int h = gid >> 8, i = gid & 255;
    w_t[(size_t)i * N_H + h] = w_h[gid];
}

// permlane32_swap-based cross-half sum: (a,b)=swap(x,x) gives a={lo,lo},
// b={hi,hi}; a+b = x[l] + x[l^32] on every lane. Pure VALU, bit-identical to
// x + __shfl_xor(x,32) (FP add commutes).
__device__ __forceinline__ float xadd32(float x) {
    float a = x, b = x;
    asm("v_permlane32_swap_b32 %0, %1" : "+v"(a), "+v"(b));
    return a + b;
}

struct IdxSet { uint4 a, b, c, d; };   // 16 u32 byte-offsets (this lane-half)

// ---------------- Kernel 12: fused sparse synapse + LIF scan, tile-32 ----------------
// Round-16: OCCUPANCY. r4's VALU cut dropped VALUBusy 61->46% but wall only
// -8% -> a ~1090 cyc/2t non-VALU floor (LDS gather + exposed latency) at the
// LDS-capped 2 waves/SIMD (65.8 KB/block). Fix: 32-col tiles - LDS/block
// 32.9 KB -> 4 blocks/CU = 4 waves/SIMD (grid 1024 = 32 tiles x 32 bgs),
// doubling both LDS-issue parallelism and latency hiding. One h-col per lane
// (lanes 0-31; upper half duplicates), halves still split the index list
// even/odd -> per-column accumulation chain order UNCHANGED -> spikes
// bit-identical. zmask becomes 1 u32 per (t, tile): bit j = h = tile*32+j.
// LDS bytes per CU per t unchanged (2x waves x half row size); VALU rises
// ~x1.6 total (scalar adds, 2x waves) into the 54% idle issue slots.
__global__ __launch_bounds__(256) void k_lif(const uint32_t* __restrict__ pm,
                                             const uint16_t* __restrict__ pt,
                                             const uint32_t* __restrict__ cnts,
                                             const float* __restrict__ w_t,
                                             uint32_t* __restrict__ zmask) {
    extern __shared__ __align__(16) float wl[];   // 257*32 floats = 32,896 B
    const int bg = blockIdx.x >> 5, tile = blockIdx.x & 31;
    const int h0 = tile * 32, tid = threadIdx.x;

    #pragma unroll 8
    for (int k = 0; k < 8; ++k) {                 // 256 rows x 8 float4 = 2048
        int idx = (k << 8) + tid;
        int i = idx >> 3, c4 = (idx & 7) << 2;
        *(float4*)(wl + i * 32 + c4) =
            *(const float4*)(w_t + (size_t)i * N_H + h0 + c4);
    }
    if (tid < 32) wl[256 * 32 + tid] = 0.0f;      // sentinel row
    __syncthreads();

    const int wv = __builtin_amdgcn_readfirstlane(tid >> 6);  // uniform wave id 0..3
    const int b  = (bg << 2) + wv;                // one b per wave, uniform
    const int l  = tid & 63;
    const int col = l & 31;                       // h-column of this lane
    const int half32 = (l >> 5) << 4;             // u32 units: lane-half group
    const char* wlb = (const char*)wl + (col << 2);   // per-lane LDS base

    // Opaque zero in a VGPR: keeps cnts loads in the vmcnt domain.
    int vzero;
    asm("v_mov_b32 %0, 0" : "=v"(vzero));

    uint32_t cW0, cW1, cW2, cW3;                  // counts (VGPR, lane-uniform)
    IdxSet W0, W1, W2, W3;

#define LOADSET(CN, S, ROW) { \
    uint32_t ro_ = (uint32_t)(ROW); \
    CN = *(cnts + ro_ + vzero); \
    const uint4* mp_ = (const uint4*)(pm + ro_ * 32u + half32); \
    S.a = mp_[0]; S.b = mp_[1]; S.c = mp_[2]; S.d = mp_[3]; }

// 4 pre-shifted byte offsets -> 1 v_add + ds_read_b32 + v_add_f32 per index.
// Sentinel offset 32768 = zeroed row 256 (+0.0f).
#define GCHUNK4(G, Q) { \
    G += *(const float*)(wlb + (Q).x); \
    G += *(const float*)(wlb + (Q).y); \
    G += *(const float*)(wlb + (Q).z); \
    G += *(const float*)(wlb + (Q).w); }

// Unconditional 16-slot main gather (sentinel slots add +0.0f); per-column
// chain order identical to all prior rounds.
#define GATHER_MAIN(G, S) { \
    GCHUNK4(G, S.a) GCHUNK4(G, S.b) GCHUNK4(G, S.c) GCHUNK4(G, S.d) }

// Rare (~7%) tail for cnt > 32: raw u16 slots, same guard ladder and
// accumulation order as before.
#define GTCHUNK(G, U0, U1) { \
    uint32_t ia0 = (U0) & 0xFFFFu; \
    uint32_t ia1 = (U0) >> 16; \
    uint32_t ia2 = (U1) & 0xFFFFu; \
    uint32_t ia3 = (U1) >> 16; \
    G += *(wl + ia0 * 32 + col); \
    G += *(wl + ia1 * 32 + col); \
    G += *(wl + ia2 * 32 + col); \
    G += *(wl + ia3 * 32 + col); }

#define GATHER_TAIL(G, CN, ROW) do { \
    uint32_t cs = __builtin_amdgcn_readfirstlane(CN); \
    if (cs > 32u) { \
        uint32_t ro_ = (uint32_t)(ROW); \
        const uint4* tp = (const uint4*)(pt + ro_ * 32u + half32); \
        uint4 T0 = tp[0], T1 = tp[1]; \
        GTCHUNK(G, T0.x, T0.y) \
        if (cs > 40u) GTCHUNK(G, T0.z, T0.w) \
        if (cs > 48u) GTCHUNK(G, T1.x, T1.y) \
        if (cs > 56u) GTCHUNK(G, T1.z, T1.w) \
    } } while (0)

// One LIF step: identical math/order to all prior rounds (per column).
#define SCANSTEP(G, ROW) { \
    float c = xadd32(G); \
    s0 = __builtin_fmaf(s0, 0.875f, c); \
    v0 = __builtin_fmaf(0.125f, s0 - v0, v0); \
    unsigned long long m = __ballot(v0 > 1.0f); \
    if (v0 > 1.0f) v0 = 0.0f; \
    if (l == 0) zmask[(uint32_t)((ROW) * 32 + tile)] = (uint32_t)m; }

    float v0 = 0, s0 = 0;
    LOADSET(cW0, W0, b);                         // idx(0)
    LOADSET(cW1, W1, BATCH + b);                 // idx(1)
    LOADSET(cW2, W2, 2 * BATCH + b);             // idx(2)
    LOADSET(cW3, W3, 3 * BATCH + b);             // idx(3)

    for (int t = 0; t < T_STEPS; t += 4) {
        const int rowA = t * BATCH + b;
        const int rowB = rowA + BATCH;
        const int rowC = rowB + BATCH;
        const int rowD = rowC + BATCH;

        // ---- body 1: steps t, t+1 from W0/W1; refill W0/W1 <- t+4, t+5 ----
        float ga = 0.0f, gb = 0.0f;
        GATHER_MAIN(ga, W0);
        GATHER_MAIN(gb, W1);
        GATHER_TAIL(ga, cW0, rowA);
        GATHER_TAIL(gb, cW1, rowB);
        {
            int r4 = t + 4; if (r4 > T_STEPS - 1) r4 = T_STEPS - 1;
            int r5 = t + 5; if (r5 > T_STEPS - 1) r5 = T_STEPS - 1;
            LOADSET(cW0, W0, r4 * BATCH + b);
            LOADSET(cW1, W1, r5 * BATCH + b);
        }
        SCANSTEP(ga, rowA);
        SCANSTEP(gb, rowB);

        // ---- body 2: steps t+2, t+3 from W2/W3; refill W2/W3 <- t+6, t+7 ----
        float gc = 0.0f, gd = 0.0f;
        GATHER_MAIN(gc, W2);
        GATHER_MAIN(gd, W3);
        GATHER_TAIL(gc, cW2, rowC);
        GATHER_TAIL(gd, cW3, rowD);
        {
            int r6 = t + 6; if (r6 > T_STEPS - 1) r6 = T_STEPS - 1;
            int r7 = t + 7; if (r7 > T_STEPS - 1) r7 = T_STEPS - 1;
            LOADSET(cW2, W2, r6 * BATCH + b);
            LOADSET(cW3, W3, r7 * BATCH + b);
        }
        SCANSTEP(gc, rowC);
        SCANSTEP(gd, rowD);
    }
#undef LOADSET
#undef GCHUNK4
#undef GATHER_MAIN
#undef GTCHUNK
#undef GATHER_TAIL
#undef SCANSTEP
}

// DPP partial-sum ladder step: returns x shifted by CTRL (invalid lanes -> 0),
// pure VALU, hazards handled by the backend (GCNDPPCombine folds the mov into
// the consuming v_add -> v_add_f32_dpp).
#define DPP_TERM(X, CTRL) \
    __int_as_float(__builtin_amdgcn_update_dpp(0, __float_as_int(X), CTRL, 0xF, 0xF, true))

// ---------------- Kernel 34: output synapse + LI scan, 4-way t-split ----------------
// zmask word = 32-col tile, bit j = h = word*32+j -> wo staging is a linear
// copy. DPP add ladder (row_shr:1/2/4/8 + row_bcast:15); sum lands in lane 31
// of each 32-lane group -> store predicate word==31. Segment scheme unchanged.
__global__ __launch_bounds__(256) void k_li(const uint32_t* __restrict__ zmask,
                                            const float* __restrict__ w_o,
                                            float* __restrict__ out,
                                            float2* __restrict__ svbuf) {
    extern __shared__ __align__(16) float wo[];   // 8 * 1025 floats = 32,800 B
    const int gb  = blockIdx.x;                   // seg(4) x b(128) x oct(4)
    const int seg = gb >> 9;
    const int rem = gb & 511;
    const int b   = rem >> 2;
    const int oct = rem & 3;
    const int o0  = oct << 3;
    const int tid = threadIdx.x;
    for (int lin = tid; lin < 8 * 1024; lin += 256) {
        int ol = lin >> 10, idx = lin & 1023;     // h = idx (linear map)
        wo[ol * 1025 + idx] = w_o[(size_t)(o0 + ol) * N_H + idx];
    }
    __syncthreads();

    const int ol = tid >> 5, word = tid & 31;
    const float* wrow = wo + ol * 1025 + (word << 5);
    const int t0 = seg << 7, t1 = t0 + 128;

    float v = 0.0f, s = 0.0f;
    uint32_t mA = zmask[(size_t)(t0 * BATCH + b) * 32 + word];
    uint32_t mB = zmask[(size_t)((t0 + 1) * BATCH + b) * 32 + word];
    for (int t = t0; t < t1; t += 2) {
        uint32_t ma = mA, mb = mB;
        int ta = (t + 2 < t1) ? t + 2 : t;
        int tb = (t + 3 < t1) ? t + 3 : t;
        mA = zmask[(size_t)(ta * BATCH + b) * 32 + word];
        mB = zmask[(size_t)(tb * BATCH + b) * 32 + word];

        float c0 = 0.0f, c1 = 0.0f;
        while (ma) { int j = __builtin_ctz(ma); ma &= ma - 1; c0 += wrow[j]; }
        while (mb) { int j = __builtin_ctz(mb); mb &= mb - 1; c1 += wrow[j]; }

        // interleaved DPP reductions (independent chains overlap, pure VALU)
        c0 += DPP_TERM(c0, 0x111);  c1 += DPP_TERM(c1, 0x111);  // row_shr:1
        c0 += DPP_TERM(c0, 0x112);  c1 += DPP_TERM(c1, 0x112);  // row_shr:2
        c0 += DPP_TERM(c0, 0x114);  c1 += DPP_TERM(c1, 0x114);  // row_shr:4
        c0 += DPP_TERM(c0, 0x118);  c1 += DPP_TERM(c1, 0x118);  // row_shr:8
        c0 += DPP_TERM(c0, 0x142);  c1 += DPP_TERM(c1, 0x142);  // row_bcast:15

        s = __builtin_fmaf(s, 0.875f, c0);
        v = __builtin_fmaf(0.125f, s - v, v);
        if (word == 31)
            out[(size_t)(t * BATCH + b) * 32 + o0 + ol] = v;

        s = __builtin_fmaf(s, 0.875f, c1);
        v = __builtin_fmaf(0.125f, s - v, v);
        if (word == 31)
            out[(size_t)((t + 1) * BATCH + b) * 32 + o0 + ol] = v;
    }
    if (word == 31)                       // zero-run end state of this segment
        svbuf[((size_t)seg * BATCH + b) * 32 + o0 + ol] = make_float2(s, v);
}

// ---------------- Kernel F: add homogeneous LI correction for segs 1..3 ----------------
// M^k on (i,v): i->a^k i ; v->a^k v + 0.125 k a^k i  (a = 0.875, equal
// eigenvalues). True seg start = prev zero-run ends composed through M^128.
__global__ __launch_bounds__(256) void k_fix(const float2* __restrict__ svbuf,
                                             float* __restrict__ out) {
    int idx = blockIdx.x * 256 + threadIdx.x;     // 384*128*32 elements
    int o = idx & 31;
    int r = idx >> 5;
    int b = r & 127;
    int t = 128 + (r >> 7);                       // t in [128, 512)
    int seg = t >> 7;
    int k = (t & 127) + 1;
    const float A128 = 3.7714379e-8f;             // 0.875^128
    const float C128 = 6.0343007e-7f;             // 0.125*128*A128
    float2 S = svbuf[(size_t)b * 32 + o];         // true state entering seg 1
    if (seg >= 2) {
        float2 z = svbuf[((size_t)BATCH + b) * 32 + o];
        S = make_float2(z.x + A128 * S.x, z.y + A128 * S.y + C128 * S.x);
    }
    if (seg >= 3) {
        float2 z = svbuf[((size_t)2 * BATCH + b) * 32 + o];
        S = make_float2(z.x + A128 * S.x, z.y + A128 * S.y + C128 * S.x);
    }
    float ak = exp2f((float)k * -0.19264508f);    // 0.875^k
    float corr = __builtin_fmaf(ak, S.y, 0.125f * (float)k * ak * S.x);
    out[(size_t)(t * BATCH + b) * 32 + o] += corr;
}

// ---------------- launch ----------------
extern "C" void kernel_launch(void* const* d_in, const int* in_sizes, int n_in,
                              void* d_out, int out_size, void* d_ws, size_t ws_size,
                              hipStream_t stream) {
    const float* spikes = (const float*)d_in[0];
    const float* w_h    = (const float*)d_in[1];
    const float* w_o    = (const float*)d_in[2];
    float* out = (float*)d_out;

    char* ws = (char*)d_ws;
    uint32_t* pm    = (uint32_t*)(ws);                 //  8,388,608
    uint16_t* pt    = (uint16_t*)(ws + 8388608);       //  4,194,304
    uint32_t* cnts  = (uint32_t*)(ws + 12582912);      //    262,144
    float*    w_t   = (float*)   (ws + 12845056);      //  1,048,576
    uint32_t* zmask = (uint32_t*)(ws + 13893632);      //  8,388,608
    float2*   svbuf = (float2*)  (ws);                 //    131,072 (reuses pm;
                                                       //    ordered after k_lif)

    const int lds12 = (256 * 32 + 32) * 4;   // 32,896 B -> 4 blocks/CU
    const int lds34 = 8 * 1025 * 4;          // 32,800 B
    hipFuncSetAttribute((const void*)k_lif, hipFuncAttributeMaxDynamicSharedMemorySize, lds12);
    hipFuncSetAttribute((const void*)k_li,  hipFuncAttributeMaxDynamicSharedMemorySize, lds34);

    k_prep<<<(T_STEPS * BATCH) / 4, 256, 0, stream>>>(spikes, pm, pt, cnts);
    k_tr<<<(N_H * N_IN) / 256, 256, 0, stream>>>(w_h, w_t);
    k_lif<<<32 * 32, 256, lds12, stream>>>(pm, pt, cnts, w_t, zmask);
    k_li<<<4 * BATCH * 4, 256, lds34, stream>>>(zmask, w_o, out, svbuf);
    k_fix<<<(384 * BATCH * N_OUT) / 256, 256, 0, stream>>>(svbuf, out);
}

// Round 7
// 456.011 us; speedup vs baseline: 1.1684x; 1.1684x over previous
//
#include <hip/hip_runtime.h>
#include <stdint.h>

#define T_STEPS 512
#define BATCH   128
#define N_IN    256
#define N_H     1024
#define N_OUT   32

typedef __attribute__((ext_vector_type(2))) float f32x2;

// Workspace layout (22,282,240 B; capacity proven in round 4):
//   pm    u32[65536][32]  @ 0          8,388,608  (main idx, pre-mult <<8)
//   pt    u16[65536][32]  @ 8388608    4,194,304  (tail idx, raw)
//   cnts  u32[65536]      @ 12582912     262,144
//   w_t   f32[256][1024]  @ 12845056   1,048,576
//   zmask u32[65536][32]  @ 13893632   8,388,608  (r4 map: word=2*tile+p, bit j -> h=tile*64+2j+p)

// ---------------- Kernel A: compact spike indices, 4 rows per block ----------------
// pm slots 0-15 = even list positions, 16-31 = odd, stored as byte offsets
// (idx<<8 for the 256 B tile-64 rows; sentinel 256<<8 = zeroed row 256).
// pt = raw u16 tail (slots 32-63). cnts[row] = active count.
__global__ __launch_bounds__(256) void k_prep(const float* __restrict__ spikes,
                                              uint32_t* __restrict__ pm,
                                              uint16_t* __restrict__ pt,
                                              uint32_t* __restrict__ cnts) {
    __shared__ uint16_t list[64];
    __shared__ uint32_t wcnt[4];
    const int tid = threadIdx.x;
    const int wave = tid >> 6, lane = tid & 63;
    for (int r = 0; r < 4; ++r) {
        const int row = blockIdx.x * 4 + r;        // t*BATCH + b
        float s = spikes[(size_t)row * N_IN + tid];
        bool act = s > 0.5f;                       // spikes are exactly 0.0/1.0
        unsigned long long m = __ballot(act);
        if (tid < 64) list[tid] = 256;             // sentinel
        if (lane == 0) wcnt[wave] = (uint32_t)__popcll(m);
        __syncthreads();
        uint32_t off = 0;
        for (int w = 0; w < wave; ++w) off += wcnt[w];
        uint32_t total = wcnt[0] + wcnt[1] + wcnt[2] + wcnt[3];
        if (act) {
            uint32_t pos = off + (uint32_t)__popcll(m & ((1ull << lane) - 1ull));
            if (pos < 64) list[pos] = (uint16_t)tid;   // ascending input index order
        }
        __syncthreads();
        if (tid < 32) {                        // main: u32 byte offsets (<<8)
            int h = tid >> 4, sl = tid & 15;
            pm[(uint32_t)row * 32 + tid] = ((uint32_t)list[2 * sl + h]) << 8;
        } else if (tid < 64) {                 // tail: raw u16
            int u = tid & 31;
            int h = u >> 4, sl = u & 15;
            pt[(uint32_t)row * 32 + u] = list[32 + 2 * sl + h];
        }
        if (tid == 0) cnts[row] = total < 64u ? total : 64u;
        __syncthreads();
    }
}

// ---------------- Kernel T: transpose w_h[h][i] -> w_t[i][h] ----------------
__global__ __launch_bounds__(256) void k_tr(const float* __restrict__ w_h,
                                            float* __restrict__ w_t) {
    int gid = blockIdx.x * 256 + threadIdx.x;   // 262144 elements
    int h = gid >> 8, i = gid & 255;
    w_t[(size_t)i * N_H + h] = w_h[gid];
}

// permlane32_swap-based cross-half sum: (a,b)=swap(x,x) gives a={lo,lo},
// b={hi,hi}; a+b = x[l] + x[l^32] on every lane. Pure VALU, bit-identical to
// x + __shfl_xor(x,32) (FP add commutes).
__device__ __forceinline__ float xadd32(float x) {
    float a = x, b = x;
    asm("v_permlane32_swap_b32 %0, %1" : "+v"(a), "+v"(b));
    return a + b;
}

struct IdxSet { uint4 a, b, c, d; };   // 16 u32 byte-offsets (this lane-half)

// ---------------- Kernel 12: fused sparse synapse + LIF scan (r4 verbatim) ----------------
// Round-17/18: the round-4 tile-64 configuration (215.5 us measured). r5's
// tile-32 probe established the cycle model: the LDS pipe charges ~6 cyc PER
// INSTRUCTION (b32 or b64 alike) - r5 = 16 waves x 16 ds_read_b32 x 5.8 =
// 1484 cyc/t/CU floor, measured 1529. r4 = 8 waves x 16 ds_read_b64 x 6 =
// 768 cyc/t/CU, measured 1010 -> r4 is ~76% LDS-pipe-bound, near its
// structural floor. Remaining k_lif headroom <= ~25%; effort goes to k_li.
// Spikes bit-identical to all prior rounds.
__global__ __launch_bounds__(256) void k_lif(const uint32_t* __restrict__ pm,
                                             const uint16_t* __restrict__ pt,
                                             const uint32_t* __restrict__ cnts,
                                             const float* __restrict__ w_t,
                                             uint32_t* __restrict__ zmask) {
    extern __shared__ __align__(16) float wl[];   // 257*64 floats = 65,792 B
    const int bg = blockIdx.x >> 4, tile = blockIdx.x & 15;
    const int h0 = tile * 64, tid = threadIdx.x;

    #pragma unroll 8
    for (int k = 0; k < 16; ++k) {                // 256 rows x 16 float4 = 4096
        int idx = (k << 8) + tid;
        int i = idx >> 4, c4 = (idx & 15) << 2;
        *(float4*)(wl + i * 64 + c4) =
            *(const float4*)(w_t + (size_t)i * N_H + h0 + c4);
    }
    if (tid < 64) wl[256 * 64 + tid] = 0.0f;      // sentinel row
    __syncthreads();

    const int wv = __builtin_amdgcn_readfirstlane(tid >> 6);  // uniform wave id 0..3
    const int b  = (bg << 2) + wv;                // one b per wave, uniform
    const int l  = tid & 63;
    const int duo2 = (l & 31) << 1;               // float offset of h-duo
    const int half16 = (l >> 5) << 4;             // u16 units: lane-half group
    const int half32 = (l >> 5) << 4;             // u32 units: lane-half group
    const char* wlb = (const char*)wl + (duo2 << 2);  // per-lane LDS base

    // Opaque zero in a VGPR: keeps cnts loads in the vmcnt domain.
    int vzero;
    asm("v_mov_b32 %0, 0" : "=v"(vzero));

    uint32_t cW0, cW1, cW2, cW3;                  // counts (VGPR, lane-uniform)
    IdxSet W0, W1, W2, W3;

#define LOADSET(CN, S, ROW) { \
    uint32_t ro_ = (uint32_t)(ROW); \
    CN = *(cnts + ro_ + vzero); \
    const uint4* mp_ = (const uint4*)(pm + ro_ * 32u + half32); \
    S.a = mp_[0]; S.b = mp_[1]; S.c = mp_[2]; S.d = mp_[3]; }

// 4 pre-multiplied byte offsets -> 1 v_add + ds_read_b64 + pk_add per index.
// Sentinel offset 65536 = zeroed sentinel row (+0.0f).
#define GCHUNK4(G, Q) { \
    G += *(const f32x2*)(wlb + (Q).x); \
    G += *(const f32x2*)(wlb + (Q).y); \
    G += *(const f32x2*)(wlb + (Q).z); \
    G += *(const f32x2*)(wlb + (Q).w); }

// Unconditional 16-slot main gather (sentinel slots add +0.0f); chain order
// identical to all prior rounds.
#define GATHER_MAIN(G, S) { \
    GCHUNK4(G, S.a) GCHUNK4(G, S.b) GCHUNK4(G, S.c) GCHUNK4(G, S.d) }

// Rare (~7%) tail for cnt > 32: raw u16 slots, same guard ladder and
// accumulation order as before.
#define GTCHUNK(G, U0, U1) { \
    uint32_t ia0 = (U0) & 0xFFFFu; \
    uint32_t ia1 = (U0) >> 16; \
    uint32_t ia2 = (U1) & 0xFFFFu; \
    uint32_t ia3 = (U1) >> 16; \
    G += *(const f32x2*)(wl + ia0 * 64 + duo2); \
    G += *(const f32x2*)(wl + ia1 * 64 + duo2); \
    G += *(const f32x2*)(wl + ia2 * 64 + duo2); \
    G += *(const f32x2*)(wl + ia3 * 64 + duo2); }

#define GATHER_TAIL(G, CN, ROW) do { \
    uint32_t cs = __builtin_amdgcn_readfirstlane(CN); \
    if (cs > 32u) { \
        uint32_t ro_ = (uint32_t)(ROW); \
        const uint4* tp = (const uint4*)(pt + ro_ * 32u + half16); \
        uint4 T0 = tp[0], T1 = tp[1]; \
        GTCHUNK(G, T0.x, T0.y) \
        if (cs > 40u) GTCHUNK(G, T0.z, T0.w) \
        if (cs > 48u) GTCHUNK(G, T1.x, T1.y) \
        if (cs > 56u) GTCHUNK(G, T1.z, T1.w) \
    } } while (0)

// One LIF step: identical math/order to all prior rounds.
#define SCANSTEP(G, ROW) { \
    float c0 = xadd32(G.x); \
    float c1 = xadd32(G.y); \
    s0 = __builtin_fmaf(s0, 0.875f, c0); \
    s1 = __builtin_fmaf(s1, 0.875f, c1); \
    v0 = __builtin_fmaf(0.125f, s0 - v0, v0); \
    v1 = __builtin_fmaf(0.125f, s1 - v1, v1); \
    unsigned long long m0 = __ballot(v0 > 1.0f); \
    unsigned long long m1 = __ballot(v1 > 1.0f); \
    if (v0 > 1.0f) v0 = 0.0f; \
    if (v1 > 1.0f) v1 = 0.0f; \
    if (l == 0) { \
        uint2* zp = (uint2*)(zmask + (uint32_t)((ROW) * 32 + (tile << 1))); \
        *zp = make_uint2((uint32_t)m0, (uint32_t)m1); } }

    float v0 = 0, v1 = 0, s0 = 0, s1 = 0;
    LOADSET(cW0, W0, b);                         // idx(0)
    LOADSET(cW1, W1, BATCH + b);                 // idx(1)
    LOADSET(cW2, W2, 2 * BATCH + b);             // idx(2)
    LOADSET(cW3, W3, 3 * BATCH + b);             // idx(3)

    for (int t = 0; t < T_STEPS; t += 4) {
        const int rowA = t * BATCH + b;
        const int rowB = rowA + BATCH;
        const int rowC = rowB + BATCH;
        const int rowD = rowC + BATCH;

        // ---- body 1: steps t, t+1 from W0/W1; refill W0/W1 <- t+4, t+5 ----
        f32x2 ga = {0.0f, 0.0f}, gb = {0.0f, 0.0f};
        GATHER_MAIN(ga, W0);
        GATHER_MAIN(gb, W1);
        GATHER_TAIL(ga, cW0, rowA);
        GATHER_TAIL(gb, cW1, rowB);
        {
            int r4 = t + 4; if (r4 > T_STEPS - 1) r4 = T_STEPS - 1;
            int r5 = t + 5; if (r5 > T_STEPS - 1) r5 = T_STEPS - 1;
            LOADSET(cW0, W0, r4 * BATCH + b);
            LOADSET(cW1, W1, r5 * BATCH + b);
        }
        SCANSTEP(ga, rowA);
        SCANSTEP(gb, rowB);

        // ---- body 2: steps t+2, t+3 from W2/W3; refill W2/W3 <- t+6, t+7 ----
        f32x2 gc = {0.0f, 0.0f}, gd = {0.0f, 0.0f};
        GATHER_MAIN(gc, W2);
        GATHER_MAIN(gd, W3);
        GATHER_TAIL(gc, cW2, rowC);
        GATHER_TAIL(gd, cW3, rowD);
        {
            int r6 = t + 6; if (r6 > T_STEPS - 1) r6 = T_STEPS - 1;
            int r7 = t + 7; if (r7 > T_STEPS - 1) r7 = T_STEPS - 1;
            LOADSET(cW2, W2, r6 * BATCH + b);
            LOADSET(cW3, W3, r7 * BATCH + b);
        }
        SCANSTEP(gc, rowC);
        SCANSTEP(gd, rowD);
    }
#undef LOADSET
#undef GCHUNK4
#undef GATHER_MAIN
#undef GTCHUNK
#undef GATHER_TAIL
#undef SCANSTEP
}

// DPP partial-sum ladder step: returns x shifted by CTRL (invalid lanes -> 0),
// pure VALU, hazards handled by the backend (GCNDPPCombine folds the mov into
// the consuming v_add -> v_add_f32_dpp).
#define DPP_TERM(X, CTRL) \
    __int_as_float(__builtin_amdgcn_update_dpp(0, __float_as_int(X), CTRL, 0xF, 0xF, true))

// ---------------- Kernel 34: output synapse + LI scan, half-word split ----------------
// The ctz gather loop is DIVERGENT - per-wave cost = max over 32 distinct
// words of Binom(32,p~0.08) ~ 7 iterations vs mean 2.6 (2.7x waste), each
// with a dependent LDS read. Fix: 2 lanes per word (lane l and l^32 take the
// lo/hi 16 bits) -> max over Binom(16) ~ 4-5; halves combine via the free
// VALU permlane32_swap BEFORE the unchanged DPP ladder. Block shrinks to 4
// outputs: LDS 16.9 KB -> 8 blocks/CU (was 4), grid 4096, staging traffic
// unchanged. wo padded [word][33] -> gather banks spread (j+word) % 32.
// Linear LI layer: regroup = ulp-level only; spikes untouched.
__global__ __launch_bounds__(256) void k_li(const uint32_t* __restrict__ zmask,
                                            const float* __restrict__ w_o,
                                            float* __restrict__ out,
                                            float2* __restrict__ svbuf) {
    extern __shared__ __align__(16) float wo[];   // 4 * 32 * 33 floats = 16,896 B
    const int gb  = blockIdx.x;                   // seg(4) x b(128) x quad(8)
    const int seg = gb >> 10;
    const int rem = gb & 1023;
    const int b   = rem >> 3;
    const int o0  = (rem & 7) << 2;
    const int tid = threadIdx.x;
    for (int lin = tid; lin < 4 * 1024; lin += 256) {
        int ol = lin >> 10, idx = lin & 1023;
        int word = idx >> 5, j = idx & 31;
        int h = ((word >> 1) << 6) + (j << 1) + (word & 1);  // zmask bit -> h
        wo[ol * 1056 + word * 33 + j] = w_o[(size_t)(o0 + ol) * N_H + h];
    }
    __syncthreads();

    const int wave = tid >> 6;                    // output o0+wave (uniform/wave)
    const int word = tid & 31, hsh = ((tid >> 5) & 1) << 4;
    const float* wrow = wo + wave * 1056 + word * 33 + hsh;  // this lane's 16 slots
    const int t0 = seg << 7, t1 = t0 + 128;

    float v = 0.0f, s = 0.0f;
    uint32_t mA = zmask[(size_t)(t0 * BATCH + b) * 32 + word];
    uint32_t mB = zmask[(size_t)((t0 + 1) * BATCH + b) * 32 + word];
    for (int t = t0; t < t1; t += 2) {
        uint32_t ma = (mA >> hsh) & 0xFFFFu;
        uint32_t mb = (mB >> hsh) & 0xFFFFu;
        int ta = (t + 2 < t1) ? t + 2 : t;
        int tb = (t + 3 < t1) ? t + 3 : t;
        mA = zmask[(size_t)(ta * BATCH + b) * 32 + word];
        mB = zmask[(size_t)(tb * BATCH + b) * 32 + word];

        float c0 = 0.0f, c1 = 0.0f;
        while (ma) { int j = __builtin_ctz(ma); ma &= ma - 1; c0 += wrow[j]; }
        while (mb) { int j = __builtin_ctz(mb); mb &= mb - 1; c1 += wrow[j]; }

        // combine 16-bit halves (lanes l, l^32) then the 5-level DPP ladder;
        // independent c0/c1 chains interleave.
        c0 = xadd32(c0);            c1 = xadd32(c1);
        c0 += DPP_TERM(c0, 0x111);  c1 += DPP_TERM(c1, 0x111);  // row_shr:1
        c0 += DPP_TERM(c0, 0x112);  c1 += DPP_TERM(c1, 0x112);  // row_shr:2
        c0 += DPP_TERM(c0, 0x114);  c1 += DPP_TERM(c1, 0x114);  // row_shr:4
        c0 += DPP_TERM(c0, 0x118);  c1 += DPP_TERM(c1, 0x118);  // row_shr:8
        c0 += DPP_TERM(c0, 0x142);  c1 += DPP_TERM(c1, 0x142);  // row_bcast:15

        s = __builtin_fmaf(s, 0.875f, c0);
        v = __builtin_fmaf(0.125f, s - v, v);
        if ((tid & 63) == 31)
            out[(size_t)(t * BATCH + b) * 32 + o0 + wave] = v;

        s = __builtin_fmaf(s, 0.875f, c1);
        v = __builtin_fmaf(0.125f, s - v, v);
        if ((tid & 63) == 31)
            out[(size_t)((t + 1) * BATCH + b) * 32 + o0 + wave] = v;
    }
    if ((tid & 63) == 31)                 // zero-run end state of this segment
        svbuf[((size_t)seg * BATCH + b) * 32 + o0 + wave] = make_float2(s, v);
}

// ---------------- Kernel F: add homogeneous LI correction for segs 1..3 ----------------
// M^k on (i,v): i->a^k i ; v->a^k v + 0.125 k a^k i  (a = 0.875, equal
// eigenvalues). True seg start = prev zero-run ends composed through M^128.
__global__ __launch_bounds__(256) void k_fix(const float2* __restrict__ svbuf,
                                             float* __restrict__ out) {
    int idx = blockIdx.x * 256 + threadIdx.x;     // 384*128*32 elements
    int o = idx & 31;
    int r = idx >> 5;
    int b = r & 127;
    int t = 128 + (r >> 7);                       // t in [128, 512)
    int seg = t >> 7;
    int k = (t & 127) + 1;
    const float A128 = 3.7714379e-8f;             // 0.875^128
    const float C128 = 6.0343007e-7f;             // 0.125*128*A128
    float2 S = svbuf[(size_t)b * 32 + o];         // true state entering seg 1
    if (seg >= 2) {
        float2 z = svbuf[((size_t)BATCH + b) * 32 + o];
        S = make_float2(z.x + A128 * S.x, z.y + A128 * S.y + C128 * S.x);
    }
    if (seg >= 3) {
        float2 z = svbuf[((size_t)2 * BATCH + b) * 32 + o];
        S = make_float2(z.x + A128 * S.x, z.y + A128 * S.y + C128 * S.x);
    }
    float ak = exp2f((float)k * -0.19264508f);    // 0.875^k
    float corr = __builtin_fmaf(ak, S.y, 0.125f * (float)k * ak * S.x);
    out[(size_t)(t * BATCH + b) * 32 + o] += corr;
}

// ---------------- launch ----------------
extern "C" void kernel_launch(void* const* d_in, const int* in_sizes, int n_in,
                              void* d_out, int out_size, void* d_ws, size_t ws_size,
                              hipStream_t stream) {
    const float* spikes = (const float*)d_in[0];
    const float* w_h    = (const float*)d_in[1];
    const float* w_o    = (const float*)d_in[2];
    float* out = (float*)d_out;

    char* ws = (char*)d_ws;
    uint32_t* pm    = (uint32_t*)(ws);                 //  8,388,608
    uint16_t* pt    = (uint16_t*)(ws + 8388608);       //  4,194,304
    uint32_t* cnts  = (uint32_t*)(ws + 12582912);      //    262,144
    float*    w_t   = (float*)   (ws + 12845056);      //  1,048,576
    uint32_t* zmask = (uint32_t*)(ws + 13893632);      //  8,388,608
    float2*   svbuf = (float2*)  (ws);                 //    131,072 (reuses pm;
                                                       //    ordered after k_lif)

    const int lds12 = (256 * 64 + 64) * 4;   // 65,792 B -> 2 blocks/CU
    const int lds34 = 4 * 1056 * 4;          // 16,896 B -> 8 blocks/CU
    hipFuncSetAttribute((const void*)k_lif, hipFuncAttributeMaxDynamicSharedMemorySize, lds12);
    hipFuncSetAttribute((const void*)k_li,  hipFuncAttributeMaxDynamicSharedMemorySize, lds34);

    k_prep<<<(T_STEPS * BATCH) / 4, 256, 0, stream>>>(spikes, pm, pt, cnts);
    k_tr<<<(N_H * N_IN) / 256, 256, 0, stream>>>(w_h, w_t);
    k_lif<<<512, 256, lds12, stream>>>(pm, pt, cnts, w_t, zmask);
    k_li<<<4 * BATCH * 8, 256, lds34, stream>>>(zmask, w_o, out, svbuf);
    k_fix<<<(384 * BATCH * N_OUT) / 256, 256, 0, stream>>>(svbuf, out);
}

// Round 9
// 400.896 us; speedup vs baseline: 1.3291x; 1.1375x over previous
//
#include <hip/hip_runtime.h>
#include <stdint.h>

#define T_STEPS 512
#define BATCH   128
#define N_IN    256
#define N_H     1024
#define N_OUT   32

typedef __attribute__((ext_vector_type(2))) float f32x2;

// Workspace layout (22,282,240 B; capacity proven in round 4):
//   pm    u32[65536][32]  @ 0          8,388,608  (main idx, pre-mult <<8)
//   pt    u16[65536][32]  @ 8388608    4,194,304  (tail idx, raw)
//   cnts  u32[65536]      @ 12582912     262,144
//   w_t   f32[256][1024]  @ 12845056   1,048,576
//   zmask u32[65536][32]  @ 13893632   8,388,608  (word=2*tile+p, bit j -> h=tile*64+2j+p)

// ---------------- Kernel A: compact spike indices, 4 rows per block ----------------
// pm slots 0-15 = even list positions, 16-31 = odd, stored as byte offsets
// (idx<<8 for the 256 B tile-64 rows; sentinel 256<<8 = zeroed row 256).
// pt = raw u16 tail (slots 32-63). cnts[row] = active count.
__global__ __launch_bounds__(256) void k_prep(const float* __restrict__ spikes,
                                              uint32_t* __restrict__ pm,
                                              uint16_t* __restrict__ pt,
                                              uint32_t* __restrict__ cnts) {
    __shared__ uint16_t list[64];
    __shared__ uint32_t wcnt[4];
    const int tid = threadIdx.x;
    const int wave = tid >> 6, lane = tid & 63;
    for (int r = 0; r < 4; ++r) {
        const int row = blockIdx.x * 4 + r;        // t*BATCH + b
        float s = spikes[(size_t)row * N_IN + tid];
        bool act = s > 0.5f;                       // spikes are exactly 0.0/1.0
        unsigned long long m = __ballot(act);
        if (tid < 64) list[tid] = 256;             // sentinel
        if (lane == 0) wcnt[wave] = (uint32_t)__popcll(m);
        __syncthreads();
        uint32_t off = 0;
        for (int w = 0; w < wave; ++w) off += wcnt[w];
        uint32_t total = wcnt[0] + wcnt[1] + wcnt[2] + wcnt[3];
        if (act) {
            uint32_t pos = off + (uint32_t)__popcll(m & ((1ull << lane) - 1ull));
            if (pos < 64) list[pos] = (uint16_t)tid;   // ascending input index order
        }
        __syncthreads();
        if (tid < 32) {                        // main: u32 byte offsets (<<8)
            int h = tid >> 4, sl = tid & 15;
            pm[(uint32_t)row * 32 + tid] = ((uint32_t)list[2 * sl + h]) << 8;
        } else if (tid < 64) {                 // tail: raw u16
            int u = tid & 31;
            int h = u >> 4, sl = u & 15;
            pt[(uint32_t)row * 32 + u] = list[32 + 2 * sl + h];
        }
        if (tid == 0) cnts[row] = total < 64u ? total : 64u;
        __syncthreads();
    }
}

// ---------------- Kernel T: transpose w_h[h][i] -> w_t[i][h] ----------------
__global__ __launch_bounds__(256) void k_tr(const float* __restrict__ w_h,
                                            float* __restrict__ w_t) {
    int gid = blockIdx.x * 256 + threadIdx.x;   // 262144 elements
    int h = gid >> 8, i = gid & 255;
    w_t[(size_t)i * N_H + h] = w_h[gid];
}

// permlane32_swap-based cross-half sum: after swap(a,b) with a=b=x, the pair
// {a[l],b[l]} = {x[l], x[l^32]} (whichever operand-role convention the HW
// uses); a+b = x[l] + x[l^32] on every lane. Pure VALU, bit-identical to
// x + __shfl_xor(x,32) (FP add commutes).
__device__ __forceinline__ float xadd32(float x) {
    float a = x, b = x;
    asm("v_permlane32_swap_b32 %0, %1" : "+v"(a), "+v"(b));
    return a + b;
}

// Partner fetch, SEMANTICS-PROOF (round-8 post-mortem: betting on which
// operand ends {hi,hi} produced absmax 2.5 - the xadd32 identity never
// disambiguated it). After swap, {a,b} = {own, partner} as a multiset at
// every lane, so (a != x) ? a : b == x[l^32] EXACTLY under either
// convention (tie x[l]==x[l^32]: both correct; +-0 pick is value-identical).
__device__ __forceinline__ float xpick(float x) {
    float a = x, b = x;
    asm("v_permlane32_swap_b32 %0, %1" : "+v"(a), "+v"(b));
    return (a != x) ? a : b;
}

struct IdxSet { uint4 a, b, c, d; };   // 16 u32 byte-offsets (this lane-half)

// ---------------- Kernel 12: fused sparse synapse + LIF scan (r4 verbatim) ----------------
// The round-4 tile-64 configuration (215.5 us measured, reproduced r7). Cycle
// model: LDS pipe charges ~6 cyc PER INSTRUCTION - r4 = 8 waves x 16
// ds_read_b64 x 6 = 768 cyc/t/CU floor, measured 1010 -> ~76% LDS-pipe-bound,
// near the structural floor for the bit-identical (even/odd halves) gather
// order. Spikes bit-identical to all prior rounds.
__global__ __launch_bounds__(256) void k_lif(const uint32_t* __restrict__ pm,
                                             const uint16_t* __restrict__ pt,
                                             const uint32_t* __restrict__ cnts,
                                             const float* __restrict__ w_t,
                                             uint32_t* __restrict__ zmask) {
    extern __shared__ __align__(16) float wl[];   // 257*64 floats = 65,792 B
    const int bg = blockIdx.x >> 4, tile = blockIdx.x & 15;
    const int h0 = tile * 64, tid = threadIdx.x;

    #pragma unroll 8
    for (int k = 0; k < 16; ++k) {                // 256 rows x 16 float4 = 4096
        int idx = (k << 8) + tid;
        int i = idx >> 4, c4 = (idx & 15) << 2;
        *(float4*)(wl + i * 64 + c4) =
            *(const float4*)(w_t + (size_t)i * N_H + h0 + c4);
    }
    if (tid < 64) wl[256 * 64 + tid] = 0.0f;      // sentinel row
    __syncthreads();

    const int wv = __builtin_amdgcn_readfirstlane(tid >> 6);  // uniform wave id 0..3
    const int b  = (bg << 2) + wv;                // one b per wave, uniform
    const int l  = tid & 63;
    const int duo2 = (l & 31) << 1;               // float offset of h-duo
    const int half16 = (l >> 5) << 4;             // u16 units: lane-half group
    const int half32 = (l >> 5) << 4;             // u32 units: lane-half group
    const char* wlb = (const char*)wl + (duo2 << 2);  // per-lane LDS base

    // Opaque zero in a VGPR: keeps cnts loads in the vmcnt domain.
    int vzero;
    asm("v_mov_b32 %0, 0" : "=v"(vzero));

    uint32_t cW0, cW1, cW2, cW3;                  // counts (VGPR, lane-uniform)
    IdxSet W0, W1, W2, W3;

#define LOADSET(CN, S, ROW) { \
    uint32_t ro_ = (uint32_t)(ROW); \
    CN = *(cnts + ro_ + vzero); \
    const uint4* mp_ = (const uint4*)(pm + ro_ * 32u + half32); \
    S.a = mp_[0]; S.b = mp_[1]; S.c = mp_[2]; S.d = mp_[3]; }

// 4 pre-multiplied byte offsets -> 1 v_add + ds_read_b64 + pk_add per index.
// Sentinel offset 65536 = zeroed sentinel row (+0.0f).
#define GCHUNK4(G, Q) { \
    G += *(const f32x2*)(wlb + (Q).x); \
    G += *(const f32x2*)(wlb + (Q).y); \
    G += *(const f32x2*)(wlb + (Q).z); \
    G += *(const f32x2*)(wlb + (Q).w); }

// Unconditional 16-slot main gather (sentinel slots add +0.0f); chain order
// identical to all prior rounds.
#define GATHER_MAIN(G, S) { \
    GCHUNK4(G, S.a) GCHUNK4(G, S.b) GCHUNK4(G, S.c) GCHUNK4(G, S.d) }

// Rare (~7%) tail for cnt > 32: raw u16 slots, same guard ladder and
// accumulation order as before.
#define GTCHUNK(G, U0, U1) { \
    uint32_t ia0 = (U0) & 0xFFFFu; \
    uint32_t ia1 = (U0) >> 16; \
    uint32_t ia2 = (U1) & 0xFFFFu; \
    uint32_t ia3 = (U1) >> 16; \
    G += *(const f32x2*)(wl + ia0 * 64 + duo2); \
    G += *(const f32x2*)(wl + ia1 * 64 + duo2); \
    G += *(const f32x2*)(wl + ia2 * 64 + duo2); \
    G += *(const f32x2*)(wl + ia3 * 64 + duo2); }

#define GATHER_TAIL(G, CN, ROW) do { \
    uint32_t cs = __builtin_amdgcn_readfirstlane(CN); \
    if (cs > 32u) { \
        uint32_t ro_ = (uint32_t)(ROW); \
        const uint4* tp = (const uint4*)(pt + ro_ * 32u + half16); \
        uint4 T0 = tp[0], T1 = tp[1]; \
        GTCHUNK(G, T0.x, T0.y) \
        if (cs > 40u) GTCHUNK(G, T0.z, T0.w) \
        if (cs > 48u) GTCHUNK(G, T1.x, T1.y) \
        if (cs > 56u) GTCHUNK(G, T1.z, T1.w) \
    } } while (0)

// One LIF step: identical math/order to all prior rounds.
#define SCANSTEP(G, ROW) { \
    float c0 = xadd32(G.x); \
    float c1 = xadd32(G.y); \
    s0 = __builtin_fmaf(s0, 0.875f, c0); \
    s1 = __builtin_fmaf(s1, 0.875f, c1); \
    v0 = __builtin_fmaf(0.125f, s0 - v0, v0); \
    v1 = __builtin_fmaf(0.125f, s1 - v1, v1); \
    unsigned long long m0 = __ballot(v0 > 1.0f); \
    unsigned long long m1 = __ballot(v1 > 1.0f); \
    if (v0 > 1.0f) v0 = 0.0f; \
    if (v1 > 1.0f) v1 = 0.0f; \
    if (l == 0) { \
        uint2* zp = (uint2*)(zmask + (uint32_t)((ROW) * 32 + (tile << 1))); \
        *zp = make_uint2((uint32_t)m0, (uint32_t)m1); } }

    float v0 = 0, v1 = 0, s0 = 0, s1 = 0;
    LOADSET(cW0, W0, b);                         // idx(0)
    LOADSET(cW1, W1, BATCH + b);                 // idx(1)
    LOADSET(cW2, W2, 2 * BATCH + b);             // idx(2)
    LOADSET(cW3, W3, 3 * BATCH + b);             // idx(3)

    for (int t = 0; t < T_STEPS; t += 4) {
        const int rowA = t * BATCH + b;
        const int rowB = rowA + BATCH;
        const int rowC = rowB + BATCH;
        const int rowD = rowC + BATCH;

        // ---- body 1: steps t, t+1 from W0/W1; refill W0/W1 <- t+4, t+5 ----
        f32x2 ga = {0.0f, 0.0f}, gb = {0.0f, 0.0f};
        GATHER_MAIN(ga, W0);
        GATHER_MAIN(gb, W1);
        GATHER_TAIL(ga, cW0, rowA);
        GATHER_TAIL(gb, cW1, rowB);
        {
            int r4 = t + 4; if (r4 > T_STEPS - 1) r4 = T_STEPS - 1;
            int r5 = t + 5; if (r5 > T_STEPS - 1) r5 = T_STEPS - 1;
            LOADSET(cW0, W0, r4 * BATCH + b);
            LOADSET(cW1, W1, r5 * BATCH + b);
        }
        SCANSTEP(ga, rowA);
        SCANSTEP(gb, rowB);

        // ---- body 2: steps t+2, t+3 from W2/W3; refill W2/W3 <- t+6, t+7 ----
        f32x2 gc = {0.0f, 0.0f}, gd = {0.0f, 0.0f};
        GATHER_MAIN(gc, W2);
        GATHER_MAIN(gd, W3);
        GATHER_TAIL(gc, cW2, rowC);
        GATHER_TAIL(gd, cW3, rowD);
        {
            int r6 = t + 6; if (r6 > T_STEPS - 1) r6 = T_STEPS - 1;
            int r7 = t + 7; if (r7 > T_STEPS - 1) r7 = T_STEPS - 1;
            LOADSET(cW2, W2, r6 * BATCH + b);
            LOADSET(cW3, W3, r7 * BATCH + b);
        }
        SCANSTEP(gc, rowC);
        SCANSTEP(gd, rowD);
    }
#undef LOADSET
#undef GCHUNK4
#undef GATHER_MAIN
#undef GTCHUNK
#undef GATHER_TAIL
#undef SCANSTEP
}

// DPP partial-sum ladder step: returns x shifted by CTRL (invalid lanes -> 0),
// pure VALU, hazards handled by the backend (GCNDPPCombine folds the mov into
// the consuming v_add -> v_add_f32_dpp).
#define DPP_TERM(X, CTRL) \
    __int_as_float(__builtin_amdgcn_update_dpp(0, __float_as_int(X), CTRL, 0xF, 0xF, true))

// ---------------- Kernel 34: output synapse + LI scan, 4-output b128 gather ----------------
// Round-19 structure, round-8 exchange bug fixed via xpick. Amortize the mask
// scan across outputs: weights staged bit-indexed and output-interleaved
// wo4[bit][4] (+16B pad every 8 slots) so each divergent ctz iteration is ONE
// ds_read_b128 accumulating 4 outputs -> scans/(t,b) drop 32 -> 8. Lane-halves
// of a wave process t (A) and t+1 (B); after the 5-level DPP ladder lane 31
// holds c_t and xpick hands it c_{t+1} (= lane 63's value, exact). Per-output
// computation is bit-identical to the r4 k_li (same scan order, same ladder).
// Grid: seg(4) x bquad(32) x oct(8) = 1024 blocks; LDS 18,432 B.
__global__ __launch_bounds__(256) void k_li(const uint32_t* __restrict__ zmask,
                                            const float* __restrict__ w_o,
                                            float* __restrict__ out,
                                            float2* __restrict__ svbuf) {
    extern __shared__ __align__(16) float wo4[];  // 1152 slots * 16 B = 18,432 B
    const int gb  = blockIdx.x;                   // seg(4) x bquad(32) x oct(8)
    const int seg = gb >> 8;
    const int rem = gb & 255;
    const int bq  = rem >> 3;
    const int oct = rem & 7;
    const int o0  = oct << 2;
    const int tid = threadIdx.x;

    // Stage wo4[bit][o]: bit = word*32+j -> h = ((bit>>6)<<6)+((bit&31)<<1)+((bit>>5)&1);
    // slot(bit) = bit + (bit>>3)  (16B pad every 8 slots -> bank-set spread).
    for (int lin = tid; lin < 4096; lin += 256) {
        int o = lin & 3, idx = lin >> 2;
        int h = ((idx >> 6) << 6) + ((idx & 31) << 1) + ((idx >> 5) & 1);
        wo4[((idx + (idx >> 3)) << 2) + o] = w_o[(size_t)(o0 + o) * N_H + h];
    }
    __syncthreads();

    const int b    = (bq << 2) + (tid >> 6);      // one b per wave
    const int l    = tid & 63;
    const int word = l & 31;
    const int tofs = l >> 5;                      // half A: t, half B: t+1
    const uint32_t baseoff = (uint32_t)(576 * word);   // (36*word)*16 bytes
    const char* wbase = (const char*)wo4 + baseoff;
    const int t0 = seg << 7, t1 = t0 + 128;

    float s0 = 0, s1 = 0, s2 = 0, s3 = 0;
    float v0 = 0, v1 = 0, v2 = 0, v3 = 0;

    uint32_t mcur = zmask[(uint32_t)((t0 + tofs) * BATCH + b) * 32 + word];
    for (int t = t0; t < t1; t += 2) {
        uint32_t ma = mcur;
        int tp = t + 2; if (tp >= t1) tp = t0;    // dummy prefetch on last pair
        mcur = zmask[(uint32_t)((tp + tofs) * BATCH + b) * 32 + word];

        float a0 = 0.0f, a1 = 0.0f, a2 = 0.0f, a3 = 0.0f;
        while (ma) {
            int j = __builtin_ctz(ma); ma &= ma - 1;
            const float4 wv = *(const float4*)(wbase + (((j + (j >> 3)) << 4)));
            a0 += wv.x; a1 += wv.y; a2 += wv.z; a3 += wv.w;
        }

        // 5-level DPP ladder per accumulator (4 independent chains interleave);
        // each 32-lane half reduces itself; lane 31 (and 63) hold the sums.
        a0 += DPP_TERM(a0, 0x111); a1 += DPP_TERM(a1, 0x111);
        a2 += DPP_TERM(a2, 0x111); a3 += DPP_TERM(a3, 0x111);
        a0 += DPP_TERM(a0, 0x112); a1 += DPP_TERM(a1, 0x112);
        a2 += DPP_TERM(a2, 0x112); a3 += DPP_TERM(a3, 0x112);
        a0 += DPP_TERM(a0, 0x114); a1 += DPP_TERM(a1, 0x114);
        a2 += DPP_TERM(a2, 0x114); a3 += DPP_TERM(a3, 0x114);
        a0 += DPP_TERM(a0, 0x118); a1 += DPP_TERM(a1, 0x118);
        a2 += DPP_TERM(a2, 0x118); a3 += DPP_TERM(a3, 0x118);
        a0 += DPP_TERM(a0, 0x142); a1 += DPP_TERM(a1, 0x142);
        a2 += DPP_TERM(a2, 0x142); a3 += DPP_TERM(a3, 0x142);

        // at lane 31: cA_k = a_k (own half sum), cB_k = xpick(a_k) = lane 63's
        // half-B sum, exact under either permlane operand convention.
        float b0 = xpick(a0), b1 = xpick(a1), b2 = xpick(a2), b3 = xpick(a3);

        // recurrence (meaningful at lane 31; computed everywhere, stored at 31)
        s0 = __builtin_fmaf(s0, 0.875f, a0); v0 = __builtin_fmaf(0.125f, s0 - v0, v0);
        s1 = __builtin_fmaf(s1, 0.875f, a1); v1 = __builtin_fmaf(0.125f, s1 - v1, v1);
        s2 = __builtin_fmaf(s2, 0.875f, a2); v2 = __builtin_fmaf(0.125f, s2 - v2, v2);
        s3 = __builtin_fmaf(s3, 0.875f, a3); v3 = __builtin_fmaf(0.125f, s3 - v3, v3);
        if (l == 31)
            *(float4*)(out + (size_t)(t * BATCH + b) * 32 + o0) =
                make_float4(v0, v1, v2, v3);

        s0 = __builtin_fmaf(s0, 0.875f, b0); v0 = __builtin_fmaf(0.125f, s0 - v0, v0);
        s1 = __builtin_fmaf(s1, 0.875f, b1); v1 = __builtin_fmaf(0.125f, s1 - v1, v1);
        s2 = __builtin_fmaf(s2, 0.875f, b2); v2 = __builtin_fmaf(0.125f, s2 - v2, v2);
        s3 = __builtin_fmaf(s3, 0.875f, b3); v3 = __builtin_fmaf(0.125f, s3 - v3, v3);
        if (l == 31)
            *(float4*)(out + (size_t)((t + 1) * BATCH + b) * 32 + o0) =
                make_float4(v0, v1, v2, v3);
    }
    if (l == 31) {                        // zero-run end state of this segment
        float2* sp = svbuf + ((size_t)seg * BATCH + b) * 32 + o0;
        sp[0] = make_float2(s0, v0);
        sp[1] = make_float2(s1, v1);
        sp[2] = make_float2(s2, v2);
        sp[3] = make_float2(s3, v3);
    }
}

// ---------------- Kernel F: add homogeneous LI correction for segs 1..3 ----------------
// M^k on (i,v): i->a^k i ; v->a^k v + 0.125 k a^k i  (a = 0.875, equal
// eigenvalues). True seg start = prev zero-run ends composed through M^128.
__global__ __launch_bounds__(256) void k_fix(const float2* __restrict__ svbuf,
                                             float* __restrict__ out) {
    int idx = blockIdx.x * 256 + threadIdx.x;     // 384*128*32 elements
    int o = idx & 31;
    int r = idx >> 5;
    int b = r & 127;
    int t = 128 + (r >> 7);                       // t in [128, 512)
    int seg = t >> 7;
    int k = (t & 127) + 1;
    const float A128 = 3.7714379e-8f;             // 0.875^128
    const float C128 = 6.0343007e-7f;             // 0.125*128*A128
    float2 S = svbuf[(size_t)b * 32 + o];         // true state entering seg 1
    if (seg >= 2) {
        float2 z = svbuf[((size_t)BATCH + b) * 32 + o];
        S = make_float2(z.x + A128 * S.x, z.y + A128 * S.y + C128 * S.x);
    }
    if (seg >= 3) {
        float2 z = svbuf[((size_t)2 * BATCH + b) * 32 + o];
        S = make_float2(z.x + A128 * S.x, z.y + A128 * S.y + C128 * S.x);
    }
    float ak = exp2f((float)k * -0.19264508f);    // 0.875^k
    float corr = __builtin_fmaf(ak, S.y, 0.125f * (float)k * ak * S.x);
    out[(size_t)(t * BATCH + b) * 32 + o] += corr;
}

// ---------------- launch ----------------
extern "C" void kernel_launch(void* const* d_in, const int* in_sizes, int n_in,
                              void* d_out, int out_size, void* d_ws, size_t ws_size,
                              hipStream_t stream) {
    const float* spikes = (const float*)d_in[0];
    const float* w_h    = (const float*)d_in[1];
    const float* w_o    = (const float*)d_in[2];
    float* out = (float*)d_out;

    char* ws = (char*)d_ws;
    uint32_t* pm    = (uint32_t*)(ws);                 //  8,388,608
    uint16_t* pt    = (uint16_t*)(ws + 8388608);       //  4,194,304
    uint32_t* cnts  = (uint32_t*)(ws + 12582912);      //    262,144
    float*    w_t   = (float*)   (ws + 12845056);      //  1,048,576
    uint32_t* zmask = (uint32_t*)(ws + 13893632);      //  8,388,608
    float2*   svbuf = (float2*)  (ws);                 //    131,072 (reuses pm;
                                                       //    ordered after k_lif)

    const int lds12 = (256 * 64 + 64) * 4;   // 65,792 B -> 2 blocks/CU
    const int lds34 = 1152 * 16;             // 18,432 B
    hipFuncSetAttribute((const void*)k_lif, hipFuncAttributeMaxDynamicSharedMemorySize, lds12);
    hipFuncSetAttribute((const void*)k_li,  hipFuncAttributeMaxDynamicSharedMemorySize, lds34);

    k_prep<<<(T_STEPS * BATCH) / 4, 256, 0, stream>>>(spikes, pm, pt, cnts);
    k_tr<<<(N_H * N_IN) / 256, 256, 0, stream>>>(w_h, w_t);
    k_lif<<<512, 256, lds12, stream>>>(pm, pt, cnts, w_t, zmask);
    k_li<<<4 * 32 * 8, 256, lds34, stream>>>(zmask, w_o, out, svbuf);
    k_fix<<<(384 * BATCH * N_OUT) / 256, 256, 0, stream>>>(svbuf, out);
}

// Round 11
// 400.065 us; speedup vs baseline: 1.3318x; 1.0021x over previous
//
#include <hip/hip_runtime.h>
#include <stdint.h>

#define T_STEPS 512
#define BATCH   128
#define N_IN    256
#define N_H     1024
#define N_OUT   32

typedef __attribute__((ext_vector_type(2))) float f32x2;

// Workspace layout (22,282,240 B; capacity proven in round 4):
//   pm    u32[65536][32]  @ 0          8,388,608  (main idx, pre-mult <<8)
//   pt    u16[65536][32]  @ 8388608    4,194,304  (tail idx, raw)
//   cnts  u32[65536]      @ 12582912     262,144
//   w_t   f32[256][1024]  @ 12845056   1,048,576
//   zmask u32[65536][32]  @ 13893632   8,388,608  (word=2*tile+p, bit j -> h=tile*64+2j+p)

// ---------------- Kernel A: compact spike indices, 4 rows per block ----------------
// pm slots 0-15 = even list positions, 16-31 = odd, stored as byte offsets
// (idx<<8 for the 256 B tile-64 rows; sentinel 256<<8 = zeroed row 256).
// pt = raw u16 tail (slots 32-63). cnts[row] = active count.
__global__ __launch_bounds__(256) void k_prep(const float* __restrict__ spikes,
                                              uint32_t* __restrict__ pm,
                                              uint16_t* __restrict__ pt,
                                              uint32_t* __restrict__ cnts) {
    __shared__ uint16_t list[64];
    __shared__ uint32_t wcnt[4];
    const int tid = threadIdx.x;
    const int wave = tid >> 6, lane = tid & 63;
    for (int r = 0; r < 4; ++r) {
        const int row = blockIdx.x * 4 + r;        // t*BATCH + b
        float s = spikes[(size_t)row * N_IN + tid];
        bool act = s > 0.5f;                       // spikes are exactly 0.0/1.0
        unsigned long long m = __ballot(act);
        if (tid < 64) list[tid] = 256;             // sentinel
        if (lane == 0) wcnt[wave] = (uint32_t)__popcll(m);
        __syncthreads();
        uint32_t off = 0;
        for (int w = 0; w < wave; ++w) off += wcnt[w];
        uint32_t total = wcnt[0] + wcnt[1] + wcnt[2] + wcnt[3];
        if (act) {
            uint32_t pos = off + (uint32_t)__popcll(m & ((1ull << lane) - 1ull));
            if (pos < 64) list[pos] = (uint16_t)tid;   // ascending input index order
        }
        __syncthreads();
        if (tid < 32) {                        // main: u32 byte offsets (<<8)
            int h = tid >> 4, sl = tid & 15;
            pm[(uint32_t)row * 32 + tid] = ((uint32_t)list[2 * sl + h]) << 8;
        } else if (tid < 64) {                 // tail: raw u16
            int u = tid & 31;
            int h = u >> 4, sl = u & 15;
            pt[(uint32_t)row * 32 + u] = list[32 + 2 * sl + h];
        }
        if (tid == 0) cnts[row] = total < 64u ? total : 64u;
        __syncthreads();
    }
}

// ---------------- Kernel T: transpose w_h[h][i] -> w_t[i][h] ----------------
__global__ __launch_bounds__(256) void k_tr(const float* __restrict__ w_h,
                                            float* __restrict__ w_t) {
    int gid = blockIdx.x * 256 + threadIdx.x;   // 262144 elements
    int h = gid >> 8, i = gid & 255;
    w_t[(size_t)i * N_H + h] = w_h[gid];
}

// permlane32_swap-based cross-half sum: after swap(a,b) with a=b=x, the pair
// {a[l],b[l]} = {x[l], x[l^32]} (whichever operand-role convention the HW
// uses); a+b = x[l] + x[l^32] on every lane. Pure VALU, bit-identical to
// x + __shfl_xor(x,32) (FP add commutes).
__device__ __forceinline__ float xadd32(float x) {
    float a = x, b = x;
    asm("v_permlane32_swap_b32 %0, %1" : "+v"(a), "+v"(b));
    return a + b;
}

// Partner fetch, SEMANTICS-PROOF (round-8 post-mortem: betting on which
// operand ends {hi,hi} produced absmax 2.5). After swap, {a,b} = {own,
// partner} as a multiset at every lane, so (a != x) ? a : b == x[l^32]
// EXACTLY under either convention (tie: both correct).
__device__ __forceinline__ float xpick(float x) {
    float a = x, b = x;
    asm("v_permlane32_swap_b32 %0, %1" : "+v"(a), "+v"(b));
    return (a != x) ? a : b;
}

struct IdxSet { uint4 a, b, c, d; };   // 16 u32 byte-offsets (this lane-half)

// ---------------- Kernel 12: fused sparse synapse + LIF scan, 8-wave blocks ----------------
// Round-21 (rerun; r10 bench was an infra failure with no kernel verdict).
// WAVE-INTERLEAVE: r4/r9 config is ~76% LDS-pipe-bound (65536 LDS instr/CU
// over 516K cyc = 7.9 cyc/instr vs ~6 pipe cost); the 25% gap is issue
// bubbles with only 2 waves/SIMD (both can stall simultaneously on scan VALU
// + lgkm). Fix: 512-thread blocks, 8 waves each (one b per wave), grid 256 =
// 16 tiles x 16 bgs. LDS/CU unchanged (2 x 65.8 KB), waves/CU 8 -> 16 =
// 4/SIMD. Per-wave instruction stream and math BIT-IDENTICAL - only the
// wave->b packing changes. Predicted k_lif 215 -> ~180 us.
__global__ __launch_bounds__(512) void k_lif(const uint32_t* __restrict__ pm,
                                             const uint16_t* __restrict__ pt,
                                             const uint32_t* __restrict__ cnts,
                                             const float* __restrict__ w_t,
                                             uint32_t* __restrict__ zmask) {
    extern __shared__ __align__(16) float wl[];   // 257*64 floats = 65,792 B
    const int bg = blockIdx.x >> 4, tile = blockIdx.x & 15;
    const int h0 = tile * 64, tid = threadIdx.x;

    #pragma unroll 8
    for (int k = 0; k < 8; ++k) {                 // 256 rows x 16 float4 = 4096
        int idx = (k << 9) + tid;
        int i = idx >> 4, c4 = (idx & 15) << 2;
        *(float4*)(wl + i * 64 + c4) =
            *(const float4*)(w_t + (size_t)i * N_H + h0 + c4);
    }
    if (tid < 64) wl[256 * 64 + tid] = 0.0f;      // sentinel row
    __syncthreads();

    const int wv = __builtin_amdgcn_readfirstlane(tid >> 6);  // uniform wave id 0..7
    const int b  = (bg << 3) + wv;                // one b per wave, uniform
    const int l  = tid & 63;
    const int duo2 = (l & 31) << 1;               // float offset of h-duo
    const int half16 = (l >> 5) << 4;             // u16 units: lane-half group
    const int half32 = (l >> 5) << 4;             // u32 units: lane-half group
    const char* wlb = (const char*)wl + (duo2 << 2);  // per-lane LDS base

    // Opaque zero in a VGPR: keeps cnts loads in the vmcnt domain.
    int vzero;
    asm("v_mov_b32 %0, 0" : "=v"(vzero));

    uint32_t cW0, cW1, cW2, cW3;                  // counts (VGPR, lane-uniform)
    IdxSet W0, W1, W2, W3;

#define LOADSET(CN, S, ROW) { \
    uint32_t ro_ = (uint32_t)(ROW); \
    CN = *(cnts + ro_ + vzero); \
    const uint4* mp_ = (const uint4*)(pm + ro_ * 32u + half32); \
    S.a = mp_[0]; S.b = mp_[1]; S.c = mp_[2]; S.d = mp_[3]; }

// 4 pre-multiplied byte offsets -> 1 v_add + ds_read_b64 + pk_add per index.
// Sentinel offset 65536 = zeroed sentinel row (+0.0f).
#define GCHUNK4(G, Q) { \
    G += *(const f32x2*)(wlb + (Q).x); \
    G += *(const f32x2*)(wlb + (Q).y); \
    G += *(const f32x2*)(wlb + (Q).z); \
    G += *(const f32x2*)(wlb + (Q).w); }

// Unconditional 16-slot main gather (sentinel slots add +0.0f); chain order
// identical to all prior rounds.
#define GATHER_MAIN(G, S) { \
    GCHUNK4(G, S.a) GCHUNK4(G, S.b) GCHUNK4(G, S.c) GCHUNK4(G, S.d) }

// Rare (~7%) tail for cnt > 32: raw u16 slots, same guard ladder and
// accumulation order as before.
#define GTCHUNK(G, U0, U1) { \
    uint32_t ia0 = (U0) & 0xFFFFu; \
    uint32_t ia1 = (U0) >> 16; \
    uint32_t ia2 = (U1) & 0xFFFFu; \
    uint32_t ia3 = (U1) >> 16; \
    G += *(const f32x2*)(wl + ia0 * 64 + duo2); \
    G += *(const f32x2*)(wl + ia1 * 64 + duo2); \
    G += *(const f32x2*)(wl + ia2 * 64 + duo2); \
    G += *(const f32x2*)(wl + ia3 * 64 + duo2); }

#define GATHER_TAIL(G, CN, ROW) do { \
    uint32_t cs = __builtin_amdgcn_readfirstlane(CN); \
    if (cs > 32u) { \
        uint32_t ro_ = (uint32_t)(ROW); \
        const uint4* tp = (const uint4*)(pt + ro_ * 32u + half16); \
        uint4 T0 = tp[0], T1 = tp[1]; \
        GTCHUNK(G, T0.x, T0.y) \
        if (cs > 40u) GTCHUNK(G, T0.z, T0.w) \
        if (cs > 48u) GTCHUNK(G, T1.x, T1.y) \
        if (cs > 56u) GTCHUNK(G, T1.z, T1.w) \
    } } while (0)

// One LIF step: identical math/order to all prior rounds.
#define SCANSTEP(G, ROW) { \
    float c0 = xadd32(G.x); \
    float c1 = xadd32(G.y); \
    s0 = __builtin_fmaf(s0, 0.875f, c0); \
    s1 = __builtin_fmaf(s1, 0.875f, c1); \
    v0 = __builtin_fmaf(0.125f, s0 - v0, v0); \
    v1 = __builtin_fmaf(0.125f, s1 - v1, v1); \
    unsigned long long m0 = __ballot(v0 > 1.0f); \
    unsigned long long m1 = __ballot(v1 > 1.0f); \
    if (v0 > 1.0f) v0 = 0.0f; \
    if (v1 > 1.0f) v1 = 0.0f; \
    if (l == 0) { \
        uint2* zp = (uint2*)(zmask + (uint32_t)((ROW) * 32 + (tile << 1))); \
        *zp = make_uint2((uint32_t)m0, (uint32_t)m1); } }

    float v0 = 0, v1 = 0, s0 = 0, s1 = 0;
    LOADSET(cW0, W0, b);                         // idx(0)
    LOADSET(cW1, W1, BATCH + b);                 // idx(1)
    LOADSET(cW2, W2, 2 * BATCH + b);             // idx(2)
    LOADSET(cW3, W3, 3 * BATCH + b);             // idx(3)

    for (int t = 0; t < T_STEPS; t += 4) {
        const int rowA = t * BATCH + b;
        const int rowB = rowA + BATCH;
        const int rowC = rowB + BATCH;
        const int rowD = rowC + BATCH;

        // ---- body 1: steps t, t+1 from W0/W1; refill W0/W1 <- t+4, t+5 ----
        f32x2 ga = {0.0f, 0.0f}, gb = {0.0f, 0.0f};
        GATHER_MAIN(ga, W0);
        GATHER_MAIN(gb, W1);
        GATHER_TAIL(ga, cW0, rowA);
        GATHER_TAIL(gb, cW1, rowB);
        {
            int r4 = t + 4; if (r4 > T_STEPS - 1) r4 = T_STEPS - 1;
            int r5 = t + 5; if (r5 > T_STEPS - 1) r5 = T_STEPS - 1;
            LOADSET(cW0, W0, r4 * BATCH + b);
            LOADSET(cW1, W1, r5 * BATCH + b);
        }
        SCANSTEP(ga, rowA);
        SCANSTEP(gb, rowB);

        // ---- body 2: steps t+2, t+3 from W2/W3; refill W2/W3 <- t+6, t+7 ----
        f32x2 gc = {0.0f, 0.0f}, gd = {0.0f, 0.0f};
        GATHER_MAIN(gc, W2);
        GATHER_MAIN(gd, W3);
        GATHER_TAIL(gc, cW2, rowC);
        GATHER_TAIL(gd, cW3, rowD);
        {
            int r6 = t + 6; if (r6 > T_STEPS - 1) r6 = T_STEPS - 1;
            int r7 = t + 7; if (r7 > T_STEPS - 1) r7 = T_STEPS - 1;
            LOADSET(cW2, W2, r6 * BATCH + b);
            LOADSET(cW3, W3, r7 * BATCH + b);
        }
        SCANSTEP(gc, rowC);
        SCANSTEP(gd, rowD);
    }
#undef LOADSET
#undef GCHUNK4
#undef GATHER_MAIN
#undef GTCHUNK
#undef GATHER_TAIL
#undef SCANSTEP
}

// DPP partial-sum ladder step: returns x shifted by CTRL (invalid lanes -> 0),
// pure VALU, hazards handled by the backend (GCNDPPCombine folds the mov into
// the consuming v_add -> v_add_f32_dpp).
#define DPP_TERM(X, CTRL) \
    __int_as_float(__builtin_amdgcn_update_dpp(0, __float_as_int(X), CTRL, 0xF, 0xF, true))

// ---------------- Kernel 34: output synapse + LI scan, 4-output b128 gather ----------------
// r9 verified (passed, absmax = bf16 floor). Weights staged bit-indexed and
// output-interleaved wo4[bit][4] (+16B pad every 8 slots) so each divergent
// ctz iteration is ONE ds_read_b128 accumulating 4 outputs; lane-halves
// process t/t+1; after the DPP ladder lane 31 combines via xpick.
__global__ __launch_bounds__(256) void k_li(const uint32_t* __restrict__ zmask,
                                            const float* __restrict__ w_o,
                                            float* __restrict__ out,
                                            float2* __restrict__ svbuf) {
    extern __shared__ __align__(16) float wo4[];  // 1152 slots * 16 B = 18,432 B
    const int gb  = blockIdx.x;                   // seg(4) x bquad(32) x oct(8)
    const int seg = gb >> 8;
    const int rem = gb & 255;
    const int bq  = rem >> 3;
    const int oct = rem & 7;
    const int o0  = oct << 2;
    const int tid = threadIdx.x;

    // Stage wo4[bit][o]: bit = word*32+j -> h = ((bit>>6)<<6)+((bit&31)<<1)+((bit>>5)&1);
    // slot(bit) = bit + (bit>>3)  (16B pad every 8 slots -> bank-set spread).
    for (int lin = tid; lin < 4096; lin += 256) {
        int o = lin & 3, idx = lin >> 2;
        int h = ((idx >> 6) << 6) + ((idx & 31) << 1) + ((idx >> 5) & 1);
        wo4[((idx + (idx >> 3)) << 2) + o] = w_o[(size_t)(o0 + o) * N_H + h];
    }
    __syncthreads();

    const int b    = (bq << 2) + (tid >> 6);      // one b per wave
    const int l    = tid & 63;
    const int word = l & 31;
    const int tofs = l >> 5;                      // half A: t, half B: t+1
    const uint32_t baseoff = (uint32_t)(576 * word);   // (36*word)*16 bytes
    const char* wbase = (const char*)wo4 + baseoff;
    const int t0 = seg << 7, t1 = t0 + 128;

    float s0 = 0, s1 = 0, s2 = 0, s3 = 0;
    float v0 = 0, v1 = 0, v2 = 0, v3 = 0;

    uint32_t mcur = zmask[(uint32_t)((t0 + tofs) * BATCH + b) * 32 + word];
    for (int t = t0; t < t1; t += 2) {
        uint32_t ma = mcur;
        int tp = t + 2; if (tp >= t1) tp = t0;    // dummy prefetch on last pair
        mcur = zmask[(uint32_t)((tp + tofs) * BATCH + b) * 32 + word];

        float a0 = 0.0f, a1 = 0.0f, a2 = 0.0f, a3 = 0.0f;
        while (ma) {
            int j = __builtin_ctz(ma); ma &= ma - 1;
            const float4 wv = *(const float4*)(wbase + (((j + (j >> 3)) << 4)));
            a0 += wv.x; a1 += wv.y; a2 += wv.z; a3 += wv.w;
        }

        // 5-level DPP ladder per accumulator (4 independent chains interleave);
        // each 32-lane half reduces itself; lane 31 (and 63) hold the sums.
        a0 += DPP_TERM(a0, 0x111); a1 += DPP_TERM(a1, 0x111);
        a2 += DPP_TERM(a2, 0x111); a3 += DPP_TERM(a3, 0x111);
        a0 += DPP_TERM(a0, 0x112); a1 += DPP_TERM(a1, 0x112);
        a2 += DPP_TERM(a2, 0x112); a3 += DPP_TERM(a3, 0x112);
        a0 += DPP_TERM(a0, 0x114); a1 += DPP_TERM(a1, 0x114);
        a2 += DPP_TERM(a2, 0x114); a3 += DPP_TERM(a3, 0x114);
        a0 += DPP_TERM(a0, 0x118); a1 += DPP_TERM(a1, 0x118);
        a2 += DPP_TERM(a2, 0x118); a3 += DPP_TERM(a3, 0x118);
        a0 += DPP_TERM(a0, 0x142); a1 += DPP_TERM(a1, 0x142);
        a2 += DPP_TERM(a2, 0x142); a3 += DPP_TERM(a3, 0x142);

        // at lane 31: cA_k = a_k (own half sum), cB_k = xpick(a_k) = lane 63's
        // half-B sum, exact under either permlane operand convention.
        float b0 = xpick(a0), b1 = xpick(a1), b2 = xpick(a2), b3 = xpick(a3);

        // recurrence (meaningful at lane 31; computed everywhere, stored at 31)
        s0 = __builtin_fmaf(s0, 0.875f, a0); v0 = __builtin_fmaf(0.125f, s0 - v0, v0);
        s1 = __builtin_fmaf(s1, 0.875f, a1); v1 = __builtin_fmaf(0.125f, s1 - v1, v1);
        s2 = __builtin_fmaf(s2, 0.875f, a2); v2 = __builtin_fmaf(0.125f, s2 - v2, v2);
        s3 = __builtin_fmaf(s3, 0.875f, a3); v3 = __builtin_fmaf(0.125f, s3 - v3, v3);
        if (l == 31)
            *(float4*)(out + (size_t)(t * BATCH + b) * 32 + o0) =
                make_float4(v0, v1, v2, v3);

        s0 = __builtin_fmaf(s0, 0.875f, b0); v0 = __builtin_fmaf(0.125f, s0 - v0, v0);
        s1 = __builtin_fmaf(s1, 0.875f, b1); v1 = __builtin_fmaf(0.125f, s1 - v1, v1);
        s2 = __builtin_fmaf(s2, 0.875f, b2); v2 = __builtin_fmaf(0.125f, s2 - v2, v2);
        s3 = __builtin_fmaf(s3, 0.875f, b3); v3 = __builtin_fmaf(0.125f, s3 - v3, v3);
        if (l == 31)
            *(float4*)(out + (size_t)((t + 1) * BATCH + b) * 32 + o0) =
                make_float4(v0, v1, v2, v3);
    }
    if (l == 31) {                        // zero-run end state of this segment
        float2* sp = svbuf + ((size_t)seg * BATCH + b) * 32 + o0;
        sp[0] = make_float2(s0, v0);
        sp[1] = make_float2(s1, v1);
        sp[2] = make_float2(s2, v2);
        sp[3] = make_float2(s3, v3);
    }
}

// ---------------- Kernel F: add homogeneous LI correction for segs 1..3 ----------------
// M^k on (i,v): i->a^k i ; v->a^k v + 0.125 k a^k i  (a = 0.875, equal
// eigenvalues). True seg start = prev zero-run ends composed through M^128.
__global__ __launch_bounds__(256) void k_fix(const float2* __restrict__ svbuf,
                                             float* __restrict__ out) {
    int idx = blockIdx.x * 256 + threadIdx.x;     // 384*128*32 elements
    int o = idx & 31;
    int r = idx >> 5;
    int b = r & 127;
    int t = 128 + (r >> 7);                       // t in [128, 512)
    int seg = t >> 7;
    int k = (t & 127) + 1;
    const float A128 = 3.7714379e-8f;             // 0.875^128
    const float C128 = 6.0343007e-7f;             // 0.125*128*A128
    float2 S = svbuf[(size_t)b * 32 + o];         // true state entering seg 1
    if (seg >= 2) {
        float2 z = svbuf[((size_t)BATCH + b) * 32 + o];
        S = make_float2(z.x + A128 * S.x, z.y + A128 * S.y + C128 * S.x);
    }
    if (seg >= 3) {
        float2 z = svbuf[((size_t)2 * BATCH + b) * 32 + o];
        S = make_float2(z.x + A128 * S.x, z.y + A128 * S.y + C128 * S.x);
    }
    float ak = exp2f((float)k * -0.19264508f);    // 0.875^k
    float corr = __builtin_fmaf(ak, S.y, 0.125f * (float)k * ak * S.x);
    out[(size_t)(t * BATCH + b) * 32 + o] += corr;
}

// ---------------- launch ----------------
extern "C" void kernel_launch(void* const* d_in, const int* in_sizes, int n_in,
                              void* d_out, int out_size, void* d_ws, size_t ws_size,
                              hipStream_t stream) {
    const float* spikes = (const float*)d_in[0];
    const float* w_h    = (const float*)d_in[1];
    const float* w_o    = (const float*)d_in[2];
    float* out = (float*)d_out;

    char* ws = (char*)d_ws;
    uint32_t* pm    = (uint32_t*)(ws);                 //  8,388,608
    uint16_t* pt    = (uint16_t*)(ws + 8388608);       //  4,194,304
    uint32_t* cnts  = (uint32_t*)(ws + 12582912);      //    262,144
    float*    w_t   = (float*)   (ws + 12845056);      //  1,048,576
    uint32_t* zmask = (uint32_t*)(ws + 13893632);      //  8,388,608
    float2*   svbuf = (float2*)  (ws);                 //    131,072 (reuses pm;
                                                       //    ordered after k_lif)

    const int lds12 = (256 * 64 + 64) * 4;   // 65,792 B -> 2 blocks/CU (8 waves each)
    const int lds34 = 1152 * 16;             // 18,432 B
    hipFuncSetAttribute((const void*)k_lif, hipFuncAttributeMaxDynamicSharedMemorySize, lds12);
    hipFuncSetAttribute((const void*)k_li,  hipFuncAttributeMaxDynamicSharedMemorySize, lds34);

    k_prep<<<(T_STEPS * BATCH) / 4, 256, 0, stream>>>(spikes, pm, pt, cnts);
    k_tr<<<(N_H * N_IN) / 256, 256, 0, stream>>>(w_h, w_t);
    k_lif<<<256, 512, lds12, stream>>>(pm, pt, cnts, w_t, zmask);   // 16 tiles x 16 bgs
    k_li<<<4 * 32 * 8, 256, lds34, stream>>>(zmask, w_o, out, svbuf);
    k_fix<<<(384 * BATCH * N_OUT) / 256, 256, 0, stream>>>(svbuf, out);
}

// Round 12
// 379.403 us; speedup vs baseline: 1.4043x; 1.0545x over previous
//
#include <hip/hip_runtime.h>
#include <stdint.h>

#define T_STEPS 512
#define BATCH   128
#define N_IN    256
#define N_H     1024
#define N_OUT   32

typedef __attribute__((ext_vector_type(2))) float f32x2;

// Workspace layout (22,282,240 B; capacity proven in round 4):
//   pm    u32[65536][32]  @ 0          8,388,608  (main idx, pre-mult <<8)
//   pt    u16[65536][32]  @ 8388608    4,194,304  (tail idx, raw)
//   cnts  u32[65536]      @ 12582912     262,144
//   w_t   f32[256][1024]  @ 12845056   1,048,576
//   zmask u32[65536][32]  @ 13893632   8,388,608  (word=2*tile+p, bit j -> h=tile*64+2j+p)

// ---------------- Kernel A: compact spike indices, WAVE-PER-ROW ----------------
// Round-22: the old k_prep ran 4 rows/block with 13 __syncthreads and
// cross-wave LDS. All the work is wave-local: ballots are wave-uniform
// SGPRs; each lane derives its compaction slot from prefix popcounts. One
// wave handles a row with ZERO barriers (per-wave DS ops are processed in
// order; wave_barrier() only pins compiler scheduling). List order (ascending
// quad q, then lane) == old (wave, lane) order -> pm/pt/cnts BIT-IDENTICAL.
// 4 waves/block x 4 rows/wave -> 16 rows/block, grid 4096.
__global__ __launch_bounds__(256) void k_prep(const float* __restrict__ spikes,
                                              uint32_t* __restrict__ pm,
                                              uint16_t* __restrict__ pt,
                                              uint32_t* __restrict__ cnts) {
    __shared__ uint16_t list[4][64];              // per-wave scratch, 512 B
    const int tid = threadIdx.x;
    const int w = tid >> 6, l = tid & 63;
    uint16_t* ls = list[w];
    const int row0 = blockIdx.x * 16 + w * 4;     // wave w -> rows row0..row0+3

    for (int r = 0; r < 4; ++r) {
        const int row = row0 + r;                 // t*BATCH + b
        ls[l] = 256;                              // sentinel init (64 slots)
        __builtin_amdgcn_wave_barrier();

        const float* sp = spikes + (size_t)row * N_IN;
        float s0 = sp[l], s1 = sp[l + 64], s2 = sp[l + 128], s3 = sp[l + 192];
        unsigned long long m0 = __ballot(s0 > 0.5f);
        unsigned long long m1 = __ballot(s1 > 0.5f);
        unsigned long long m2 = __ballot(s2 > 0.5f);
        unsigned long long m3 = __ballot(s3 > 0.5f);
        const unsigned long long low = (1ull << l) - 1ull;
        uint32_t c0 = (uint32_t)__popcll(m0);
        uint32_t c1 = (uint32_t)__popcll(m1);
        uint32_t c2 = (uint32_t)__popcll(m2);
        uint32_t c3 = (uint32_t)__popcll(m3);

        // compaction: index = 64q + l, ascending (q, l) == old (wave, lane)
        if (s0 > 0.5f) {
            uint32_t pos = (uint32_t)__popcll(m0 & low);
            if (pos < 64) ls[pos] = (uint16_t)l;
        }
        if (s1 > 0.5f) {
            uint32_t pos = c0 + (uint32_t)__popcll(m1 & low);
            if (pos < 64) ls[pos] = (uint16_t)(64 + l);
        }
        if (s2 > 0.5f) {
            uint32_t pos = c0 + c1 + (uint32_t)__popcll(m2 & low);
            if (pos < 64) ls[pos] = (uint16_t)(128 + l);
        }
        if (s3 > 0.5f) {
            uint32_t pos = c0 + c1 + c2 + (uint32_t)__popcll(m3 & low);
            if (pos < 64) ls[pos] = (uint16_t)(192 + l);
        }
        __builtin_amdgcn_wave_barrier();

        // emit: same slot->list-position maps as all prior rounds
        if (l < 32) {                             // main: u32 byte offsets (<<8)
            int p = 2 * (l & 15) + (l >> 4);
            pm[(uint32_t)row * 32 + l] = ((uint32_t)ls[p]) << 8;
        } else {                                  // tail: raw u16
            int u = l - 32;
            int p = 32 + 2 * (u & 15) + (u >> 4);
            pt[(uint32_t)row * 32 + u] = ls[p];
        }
        uint32_t total = c0 + c1 + c2 + c3;
        if (l == 0) cnts[row] = total < 64u ? total : 64u;
        __builtin_amdgcn_wave_barrier();
    }
}

// ---------------- Kernel T: transpose w_h[h][i] -> w_t[i][h] ----------------
__global__ __launch_bounds__(256) void k_tr(const float* __restrict__ w_h,
                                            float* __restrict__ w_t) {
    int gid = blockIdx.x * 256 + threadIdx.x;   // 262144 elements
    int h = gid >> 8, i = gid & 255;
    w_t[(size_t)i * N_H + h] = w_h[gid];
}

// permlane32_swap-based cross-half sum: after swap(a,b) with a=b=x, the pair
// {a[l],b[l]} = {x[l], x[l^32]} (whichever operand-role convention the HW
// uses); a+b = x[l] + x[l^32] on every lane. Pure VALU, bit-identical to
// x + __shfl_xor(x,32) (FP add commutes).
__device__ __forceinline__ float xadd32(float x) {
    float a = x, b = x;
    asm("v_permlane32_swap_b32 %0, %1" : "+v"(a), "+v"(b));
    return a + b;
}

// Partner fetch, SEMANTICS-PROOF (round-8 post-mortem: betting on which
// operand ends {hi,hi} produced absmax 2.5). After swap, {a,b} = {own,
// partner} as a multiset at every lane, so (a != x) ? a : b == x[l^32]
// EXACTLY under either convention (tie: both correct).
__device__ __forceinline__ float xpick(float x) {
    float a = x, b = x;
    asm("v_permlane32_swap_b32 %0, %1" : "+v"(a), "+v"(b));
    return (a != x) ? a : b;
}

struct IdxSet { uint4 a, b, c, d; };   // 16 u32 byte-offsets (this lane-half)

// ---------------- Kernel 12: fused sparse synapse + LIF scan (r9 verbatim) ----------------
// Round-22: REVERT to the round-9 256-thread config (215 us, measured twice).
// r11's 512-thread repack FAILED its prediction: Occupancy stayed 21% (one
// 8-wave 65.8KB block/CU instead of two 4-wave blocks - same 8 waves/CU,
// less scheduling freedom, +8 us). Per the r9 pre-commitment (k_lif >= 210
// => structural floor): the gather structure is at its LDS-pipe floor
// (~76% pipe-bound; width/occupancy/precision levers all examined & closed).
// Spikes bit-identical to all prior rounds.
__global__ __launch_bounds__(256) void k_lif(const uint32_t* __restrict__ pm,
                                             const uint16_t* __restrict__ pt,
                                             const uint32_t* __restrict__ cnts,
                                             const float* __restrict__ w_t,
                                             uint32_t* __restrict__ zmask) {
    extern __shared__ __align__(16) float wl[];   // 257*64 floats = 65,792 B
    const int bg = blockIdx.x >> 4, tile = blockIdx.x & 15;
    const int h0 = tile * 64, tid = threadIdx.x;

    #pragma unroll 8
    for (int k = 0; k < 16; ++k) {                // 256 rows x 16 float4 = 4096
        int idx = (k << 8) + tid;
        int i = idx >> 4, c4 = (idx & 15) << 2;
        *(float4*)(wl + i * 64 + c4) =
            *(const float4*)(w_t + (size_t)i * N_H + h0 + c4);
    }
    if (tid < 64) wl[256 * 64 + tid] = 0.0f;      // sentinel row
    __syncthreads();

    const int wv = __builtin_amdgcn_readfirstlane(tid >> 6);  // uniform wave id 0..3
    const int b  = (bg << 2) + wv;                // one b per wave, uniform
    const int l  = tid & 63;
    const int duo2 = (l & 31) << 1;               // float offset of h-duo
    const int half16 = (l >> 5) << 4;             // u16 units: lane-half group
    const int half32 = (l >> 5) << 4;             // u32 units: lane-half group
    const char* wlb = (const char*)wl + (duo2 << 2);  // per-lane LDS base

    // Opaque zero in a VGPR: keeps cnts loads in the vmcnt domain.
    int vzero;
    asm("v_mov_b32 %0, 0" : "=v"(vzero));

    uint32_t cW0, cW1, cW2, cW3;                  // counts (VGPR, lane-uniform)
    IdxSet W0, W1, W2, W3;

#define LOADSET(CN, S, ROW) { \
    uint32_t ro_ = (uint32_t)(ROW); \
    CN = *(cnts + ro_ + vzero); \
    const uint4* mp_ = (const uint4*)(pm + ro_ * 32u + half32); \
    S.a = mp_[0]; S.b = mp_[1]; S.c = mp_[2]; S.d = mp_[3]; }

// 4 pre-multiplied byte offsets -> 1 v_add + ds_read_b64 + pk_add per index.
// Sentinel offset 65536 = zeroed sentinel row (+0.0f).
#define GCHUNK4(G, Q) { \
    G += *(const f32x2*)(wlb + (Q).x); \
    G += *(const f32x2*)(wlb + (Q).y); \
    G += *(const f32x2*)(wlb + (Q).z); \
    G += *(const f32x2*)(wlb + (Q).w); }

// Unconditional 16-slot main gather (sentinel slots add +0.0f); chain order
// identical to all prior rounds.
#define GATHER_MAIN(G, S) { \
    GCHUNK4(G, S.a) GCHUNK4(G, S.b) GCHUNK4(G, S.c) GCHUNK4(G, S.d) }

// Rare (~7%) tail for cnt > 32: raw u16 slots, same guard ladder and
// accumulation order as before.
#define GTCHUNK(G, U0, U1) { \
    uint32_t ia0 = (U0) & 0xFFFFu; \
    uint32_t ia1 = (U0) >> 16; \
    uint32_t ia2 = (U1) & 0xFFFFu; \
    uint32_t ia3 = (U1) >> 16; \
    G += *(const f32x2*)(wl + ia0 * 64 + duo2); \
    G += *(const f32x2*)(wl + ia1 * 64 + duo2); \
    G += *(const f32x2*)(wl + ia2 * 64 + duo2); \
    G += *(const f32x2*)(wl + ia3 * 64 + duo2); }

#define GATHER_TAIL(G, CN, ROW) do { \
    uint32_t cs = __builtin_amdgcn_readfirstlane(CN); \
    if (cs > 32u) { \
        uint32_t ro_ = (uint32_t)(ROW); \
        const uint4* tp = (const uint4*)(pt + ro_ * 32u + half16); \
        uint4 T0 = tp[0], T1 = tp[1]; \
        GTCHUNK(G, T0.x, T0.y) \
        if (cs > 40u) GTCHUNK(G, T0.z, T0.w) \
        if (cs > 48u) GTCHUNK(G, T1.x, T1.y) \
        if (cs > 56u) GTCHUNK(G, T1.z, T1.w) \
    } } while (0)

// One LIF step: identical math/order to all prior rounds.
#define SCANSTEP(G, ROW) { \
    float c0 = xadd32(G.x); \
    float c1 = xadd32(G.y); \
    s0 = __builtin_fmaf(s0, 0.875f, c0); \
    s1 = __builtin_fmaf(s1, 0.875f, c1); \
    v0 = __builtin_fmaf(0.125f, s0 - v0, v0); \
    v1 = __builtin_fmaf(0.125f, s1 - v1, v1); \
    unsigned long long m0 = __ballot(v0 > 1.0f); \
    unsigned long long m1 = __ballot(v1 > 1.0f); \
    if (v0 > 1.0f) v0 = 0.0f; \
    if (v1 > 1.0f) v1 = 0.0f; \
    if (l == 0) { \
        uint2* zp = (uint2*)(zmask + (uint32_t)((ROW) * 32 + (tile << 1))); \
        *zp = make_uint2((uint32_t)m0, (uint32_t)m1); } }

    float v0 = 0, v1 = 0, s0 = 0, s1 = 0;
    LOADSET(cW0, W0, b);                         // idx(0)
    LOADSET(cW1, W1, BATCH + b);                 // idx(1)
    LOADSET(cW2, W2, 2 * BATCH + b);             // idx(2)
    LOADSET(cW3, W3, 3 * BATCH + b);             // idx(3)

    for (int t = 0; t < T_STEPS; t += 4) {
        const int rowA = t * BATCH + b;
        const int rowB = rowA + BATCH;
        const int rowC = rowB + BATCH;
        const int rowD = rowC + BATCH;

        // ---- body 1: steps t, t+1 from W0/W1; refill W0/W1 <- t+4, t+5 ----
        f32x2 ga = {0.0f, 0.0f}, gb = {0.0f, 0.0f};
        GATHER_MAIN(ga, W0);
        GATHER_MAIN(gb, W1);
        GATHER_TAIL(ga, cW0, rowA);
        GATHER_TAIL(gb, cW1, rowB);
        {
            int r4 = t + 4; if (r4 > T_STEPS - 1) r4 = T_STEPS - 1;
            int r5 = t + 5; if (r5 > T_STEPS - 1) r5 = T_STEPS - 1;
            LOADSET(cW0, W0, r4 * BATCH + b);
            LOADSET(cW1, W1, r5 * BATCH + b);
        }
        SCANSTEP(ga, rowA);
        SCANSTEP(gb, rowB);

        // ---- body 2: steps t+2, t+3 from W2/W3; refill W2/W3 <- t+6, t+7 ----
        f32x2 gc = {0.0f, 0.0f}, gd = {0.0f, 0.0f};
        GATHER_MAIN(gc, W2);
        GATHER_MAIN(gd, W3);
        GATHER_TAIL(gc, cW2, rowC);
        GATHER_TAIL(gd, cW3, rowD);
        {
            int r6 = t + 6; if (r6 > T_STEPS - 1) r6 = T_STEPS - 1;
            int r7 = t + 7; if (r7 > T_STEPS - 1) r7 = T_STEPS - 1;
            LOADSET(cW2, W2, r6 * BATCH + b);
            LOADSET(cW3, W3, r7 * BATCH + b);
        }
        SCANSTEP(gc, rowC);
        SCANSTEP(gd, rowD);
    }
#undef LOADSET
#undef GCHUNK4
#undef GATHER_MAIN
#undef GTCHUNK
#undef GATHER_TAIL
#undef SCANSTEP
}

// DPP partial-sum ladder step: returns x shifted by CTRL (invalid lanes -> 0),
// pure VALU, hazards handled by the backend (GCNDPPCombine folds the mov into
// the consuming v_add -> v_add_f32_dpp).
#define DPP_TERM(X, CTRL) \
    __int_as_float(__builtin_amdgcn_update_dpp(0, __float_as_int(X), CTRL, 0xF, 0xF, true))

// ---------------- Kernel 34: output synapse + LI scan, 4-output b128 gather ----------------
// r9 verified (passed, absmax = bf16 floor). Weights staged bit-indexed and
// output-interleaved wo4[bit][4] (+16B pad every 8 slots) so each divergent
// ctz iteration is ONE ds_read_b128 accumulating 4 outputs; lane-halves
// process t/t+1; after the DPP ladder lane 31 combines via xpick.
__global__ __launch_bounds__(256) void k_li(const uint32_t* __restrict__ zmask,
                                            const float* __restrict__ w_o,
                                            float* __restrict__ out,
                                            float2* __restrict__ svbuf) {
    extern __shared__ __align__(16) float wo4[];  // 1152 slots * 16 B = 18,432 B
    const int gb  = blockIdx.x;                   // seg(4) x bquad(32) x oct(8)
    const int seg = gb >> 8;
    const int rem = gb & 255;
    const int bq  = rem >> 3;
    const int oct = rem & 7;
    const int o0  = oct << 2;
    const int tid = threadIdx.x;

    // Stage wo4[bit][o]: bit = word*32+j -> h = ((bit>>6)<<6)+((bit&31)<<1)+((bit>>5)&1);
    // slot(bit) = bit + (bit>>3)  (16B pad every 8 slots -> bank-set spread).
    for (int lin = tid; lin < 4096; lin += 256) {
        int o = lin & 3, idx = lin >> 2;
        int h = ((idx >> 6) << 6) + ((idx & 31) << 1) + ((idx >> 5) & 1);
        wo4[((idx + (idx >> 3)) << 2) + o] = w_o[(size_t)(o0 + o) * N_H + h];
    }
    __syncthreads();

    const int b    = (bq << 2) + (tid >> 6);      // one b per wave
    const int l    = tid & 63;
    const int word = l & 31;
    const int tofs = l >> 5;                      // half A: t, half B: t+1
    const uint32_t baseoff = (uint32_t)(576 * word);   // (36*word)*16 bytes
    const char* wbase = (const char*)wo4 + baseoff;
    const int t0 = seg << 7, t1 = t0 + 128;

    float s0 = 0, s1 = 0, s2 = 0, s3 = 0;
    float v0 = 0, v1 = 0, v2 = 0, v3 = 0;

    uint32_t mcur = zmask[(uint32_t)((t0 + tofs) * BATCH + b) * 32 + word];
    for (int t = t0; t < t1; t += 2) {
        uint32_t ma = mcur;
        int tp = t + 2; if (tp >= t1) tp = t0;    // dummy prefetch on last pair
        mcur = zmask[(uint32_t)((tp + tofs) * BATCH + b) * 32 + word];

        float a0 = 0.0f, a1 = 0.0f, a2 = 0.0f, a3 = 0.0f;
        while (ma) {
            int j = __builtin_ctz(ma); ma &= ma - 1;
            const float4 wv = *(const float4*)(wbase + (((j + (j >> 3)) << 4)));
            a0 += wv.x; a1 += wv.y; a2 += wv.z; a3 += wv.w;
        }

        // 5-level DPP ladder per accumulator (4 independent chains interleave);
        // each 32-lane half reduces itself; lane 31 (and 63) hold the sums.
        a0 += DPP_TERM(a0, 0x111); a1 += DPP_TERM(a1, 0x111);
        a2 += DPP_TERM(a2, 0x111); a3 += DPP_TERM(a3, 0x111);
        a0 += DPP_TERM(a0, 0x112); a1 += DPP_TERM(a1, 0x112);
        a2 += DPP_TERM(a2, 0x112); a3 += DPP_TERM(a3, 0x112);
        a0 += DPP_TERM(a0, 0x114); a1 += DPP_TERM(a1, 0x114);
        a2 += DPP_TERM(a2, 0x114); a3 += DPP_TERM(a3, 0x114);
        a0 += DPP_TERM(a0, 0x118); a1 += DPP_TERM(a1, 0x118);
        a2 += DPP_TERM(a2, 0x118); a3 += DPP_TERM(a3, 0x118);
        a0 += DPP_TERM(a0, 0x142); a1 += DPP_TERM(a1, 0x142);
        a2 += DPP_TERM(a2, 0x142); a3 += DPP_TERM(a3, 0x142);

        // at lane 31: cA_k = a_k (own half sum), cB_k = xpick(a_k) = lane 63's
        // half-B sum, exact under either permlane operand convention.
        float b0 = xpick(a0), b1 = xpick(a1), b2 = xpick(a2), b3 = xpick(a3);

        // recurrence (meaningful at lane 31; computed everywhere, stored at 31)
        s0 = __builtin_fmaf(s0, 0.875f, a0); v0 = __builtin_fmaf(0.125f, s0 - v0, v0);
        s1 = __builtin_fmaf(s1, 0.875f, a1); v1 = __builtin_fmaf(0.125f, s1 - v1, v1);
        s2 = __builtin_fmaf(s2, 0.875f, a2); v2 = __builtin_fmaf(0.125f, s2 - v2, v2);
        s3 = __builtin_fmaf(s3, 0.875f, a3); v3 = __builtin_fmaf(0.125f, s3 - v3, v3);
        if (l == 31)
            *(float4*)(out + (size_t)(t * BATCH + b) * 32 + o0) =
                make_float4(v0, v1, v2, v3);

        s0 = __builtin_fmaf(s0, 0.875f, b0); v0 = __builtin_fmaf(0.125f, s0 - v0, v0);
        s1 = __builtin_fmaf(s1, 0.875f, b1); v1 = __builtin_fmaf(0.125f, s1 - v1, v1);
        s2 = __builtin_fmaf(s2, 0.875f, b2); v2 = __builtin_fmaf(0.125f, s2 - v2, v2);
        s3 = __builtin_fmaf(s3, 0.875f, b3); v3 = __builtin_fmaf(0.125f, s3 - v3, v3);
        if (l == 31)
            *(float4*)(out + (size_t)((t + 1) * BATCH + b) * 32 + o0) =
                make_float4(v0, v1, v2, v3);
    }
    if (l == 31) {                        // zero-run end state of this segment
        float2* sp = svbuf + ((size_t)seg * BATCH + b) * 32 + o0;
        sp[0] = make_float2(s0, v0);
        sp[1] = make_float2(s1, v1);
        sp[2] = make_float2(s2, v2);
        sp[3] = make_float2(s3, v3);
    }
}

// ---------------- Kernel F: add homogeneous LI correction for segs 1..3 ----------------
// M^k on (i,v): i->a^k i ; v->a^k v + 0.125 k a^k i  (a = 0.875, equal
// eigenvalues). True seg start = prev zero-run ends composed through M^128.
__global__ __launch_bounds__(256) void k_fix(const float2* __restrict__ svbuf,
                                             float* __restrict__ out) {
    int idx = blockIdx.x * 256 + threadIdx.x;     // 384*128*32 elements
    int o = idx & 31;
    int r = idx >> 5;
    int b = r & 127;
    int t = 128 + (r >> 7);                       // t in [128, 512)
    int seg = t >> 7;
    int k = (t & 127) + 1;
    const float A128 = 3.7714379e-8f;             // 0.875^128
    const float C128 = 6.0343007e-7f;             // 0.125*128*A128
    float2 S = svbuf[(size_t)b * 32 + o];         // true state entering seg 1
    if (seg >= 2) {
        float2 z = svbuf[((size_t)BATCH + b) * 32 + o];
        S = make_float2(z.x + A128 * S.x, z.y + A128 * S.y + C128 * S.x);
    }
    if (seg >= 3) {
        float2 z = svbuf[((size_t)2 * BATCH + b) * 32 + o];
        S = make_float2(z.x + A128 * S.x, z.y + A128 * S.y + C128 * S.x);
    }
    float ak = exp2f((float)k * -0.19264508f);    // 0.875^k
    float corr = __builtin_fmaf(ak, S.y, 0.125f * (float)k * ak * S.x);
    out[(size_t)(t * BATCH + b) * 32 + o] += corr;
}

// ---------------- launch ----------------
extern "C" void kernel_launch(void* const* d_in, const int* in_sizes, int n_in,
                              void* d_out, int out_size, void* d_ws, size_t ws_size,
                              hipStream_t stream) {
    const float* spikes = (const float*)d_in[0];
    const float* w_h    = (const float*)d_in[1];
    const float* w_o    = (const float*)d_in[2];
    float* out = (float*)d_out;

    char* ws = (char*)d_ws;
    uint32_t* pm    = (uint32_t*)(ws);                 //  8,388,608
    uint16_t* pt    = (uint16_t*)(ws + 8388608);       //  4,194,304
    uint32_t* cnts  = (uint32_t*)(ws + 12582912);      //    262,144
    float*    w_t   = (float*)   (ws + 12845056);      //  1,048,576
    uint32_t* zmask = (uint32_t*)(ws + 13893632);      //  8,388,608
    float2*   svbuf = (float2*)  (ws);                 //    131,072 (reuses pm;
                                                       //    ordered after k_lif)

    const int lds12 = (256 * 64 + 64) * 4;   // 65,792 B -> 2 blocks/CU
    const int lds34 = 1152 * 16;             // 18,432 B
    hipFuncSetAttribute((const void*)k_lif, hipFuncAttributeMaxDynamicSharedMemorySize, lds12);
    hipFuncSetAttribute((const void*)k_li,  hipFuncAttributeMaxDynamicSharedMemorySize, lds34);

    k_prep<<<(T_STEPS * BATCH) / 16, 256, 0, stream>>>(spikes, pm, pt, cnts);
    k_tr<<<(N_H * N_IN) / 256, 256, 0, stream>>>(w_h, w_t);
    k_lif<<<512, 256, lds12, stream>>>(pm, pt, cnts, w_t, zmask);
    k_li<<<4 * 32 * 8, 256, lds34, stream>>>(zmask, w_o, out, svbuf);
    k_fix<<<(384 * BATCH * N_OUT) / 256, 256, 0, stream>>>(svbuf, out);
}

// Round 13
// 373.697 us; speedup vs baseline: 1.4258x; 1.0153x over previous
//
#include <hip/hip_runtime.h>
#include <stdint.h>

#define T_STEPS 512
#define BATCH   128
#define N_IN    256
#define N_H     1024
#define N_OUT   32

typedef __attribute__((ext_vector_type(2))) float f32x2;

// Workspace layout (22,282,240 B; capacity proven in round 4):
//   pm    u32[65536][32]  @ 0          8,388,608  (main idx, pre-mult <<8)
//   pt    u16[65536][32]  @ 8388608    4,194,304  (tail idx, raw)
//   cnts  u32[65536]      @ 12582912     262,144
//   w_t   f32[256][1024]  @ 12845056   1,048,576
//   zmask u32[65536][32]  @ 13893632   8,388,608  (word=2*tile+p, bit j -> h=tile*64+2j+p)

// ---------------- Kernel A: compact spike indices, WAVE-PER-ROW (r12, verified) ----------------
// One wave per row, zero block barriers: ballots are wave-uniform SGPRs; each
// lane derives its compaction slot from prefix popcounts. List order
// (ascending quad q, then lane) == original (wave, lane) order -> pm/pt/cnts
// BIT-IDENTICAL to all prior rounds. 4 waves x 4 rows -> 16 rows/block.
__global__ __launch_bounds__(256) void k_prep(const float* __restrict__ spikes,
                                              uint32_t* __restrict__ pm,
                                              uint16_t* __restrict__ pt,
                                              uint32_t* __restrict__ cnts) {
    __shared__ uint16_t list[4][64];              // per-wave scratch, 512 B
    const int tid = threadIdx.x;
    const int w = tid >> 6, l = tid & 63;
    uint16_t* ls = list[w];
    const int row0 = blockIdx.x * 16 + w * 4;     // wave w -> rows row0..row0+3

    for (int r = 0; r < 4; ++r) {
        const int row = row0 + r;                 // t*BATCH + b
        ls[l] = 256;                              // sentinel init (64 slots)
        __builtin_amdgcn_wave_barrier();

        const float* sp = spikes + (size_t)row * N_IN;
        float s0 = sp[l], s1 = sp[l + 64], s2 = sp[l + 128], s3 = sp[l + 192];
        unsigned long long m0 = __ballot(s0 > 0.5f);
        unsigned long long m1 = __ballot(s1 > 0.5f);
        unsigned long long m2 = __ballot(s2 > 0.5f);
        unsigned long long m3 = __ballot(s3 > 0.5f);
        const unsigned long long low = (1ull << l) - 1ull;
        uint32_t c0 = (uint32_t)__popcll(m0);
        uint32_t c1 = (uint32_t)__popcll(m1);
        uint32_t c2 = (uint32_t)__popcll(m2);
        uint32_t c3 = (uint32_t)__popcll(m3);

        // compaction: index = 64q + l, ascending (q, l) == old (wave, lane)
        if (s0 > 0.5f) {
            uint32_t pos = (uint32_t)__popcll(m0 & low);
            if (pos < 64) ls[pos] = (uint16_t)l;
        }
        if (s1 > 0.5f) {
            uint32_t pos = c0 + (uint32_t)__popcll(m1 & low);
            if (pos < 64) ls[pos] = (uint16_t)(64 + l);
        }
        if (s2 > 0.5f) {
            uint32_t pos = c0 + c1 + (uint32_t)__popcll(m2 & low);
            if (pos < 64) ls[pos] = (uint16_t)(128 + l);
        }
        if (s3 > 0.5f) {
            uint32_t pos = c0 + c1 + c2 + (uint32_t)__popcll(m3 & low);
            if (pos < 64) ls[pos] = (uint16_t)(192 + l);
        }
        __builtin_amdgcn_wave_barrier();

        // emit: same slot->list-position maps as all prior rounds
        if (l < 32) {                             // main: u32 byte offsets (<<8)
            int p = 2 * (l & 15) + (l >> 4);
            pm[(uint32_t)row * 32 + l] = ((uint32_t)ls[p]) << 8;
        } else {                                  // tail: raw u16
            int u = l - 32;
            int p = 32 + 2 * (u & 15) + (u >> 4);
            pt[(uint32_t)row * 32 + u] = ls[p];
        }
        uint32_t total = c0 + c1 + c2 + c3;
        if (l == 0) cnts[row] = total < 64u ? total : 64u;
        __builtin_amdgcn_wave_barrier();
    }
}

// ---------------- Kernel T: transpose w_h[h][i] -> w_t[i][h] ----------------
__global__ __launch_bounds__(256) void k_tr(const float* __restrict__ w_h,
                                            float* __restrict__ w_t) {
    int gid = blockIdx.x * 256 + threadIdx.x;   // 262144 elements
    int h = gid >> 8, i = gid & 255;
    w_t[(size_t)i * N_H + h] = w_h[gid];
}

// permlane32_swap-based cross-half sum: after swap(a,b) with a=b=x, the pair
// {a[l],b[l]} = {x[l], x[l^32]} (whichever operand-role convention the HW
// uses); a+b = x[l] + x[l^32] on every lane. Pure VALU, bit-identical to
// x + __shfl_xor(x,32) (FP add commutes).
__device__ __forceinline__ float xadd32(float x) {
    float a = x, b = x;
    asm("v_permlane32_swap_b32 %0, %1" : "+v"(a), "+v"(b));
    return a + b;
}

// Partner fetch, SEMANTICS-PROOF (round-8 post-mortem: betting on which
// operand ends {hi,hi} produced absmax 2.5). After swap, {a,b} = {own,
// partner} as a multiset at every lane, so (a != x) ? a : b == x[l^32]
// EXACTLY under either convention (tie: both correct).
__device__ __forceinline__ float xpick(float x) {
    float a = x, b = x;
    asm("v_permlane32_swap_b32 %0, %1" : "+v"(a), "+v"(b));
    return (a != x) ? a : b;
}

struct IdxSet { uint4 a, b, c, d; };   // 16 u32 byte-offsets (this lane-half)

// ---------------- Kernel 12: fused sparse synapse + LIF scan (r9 verbatim) ----------------
// At its structural floor (215.5 us, measured 3x): ~76% LDS-pipe-bound; the
// width (b64=b128 B/cyc), occupancy (r11: 512-thr block -> 1 blk/CU, no
// gain), and tile-size (r5: tile-32 doubles instr count) levers are all
// measured and closed. Spikes bit-identical to all prior rounds.
__global__ __launch_bounds__(256) void k_lif(const uint32_t* __restrict__ pm,
                                             const uint16_t* __restrict__ pt,
                                             const uint32_t* __restrict__ cnts,
                                             const float* __restrict__ w_t,
                                             uint32_t* __restrict__ zmask) {
    extern __shared__ __align__(16) float wl[];   // 257*64 floats = 65,792 B
    const int bg = blockIdx.x >> 4, tile = blockIdx.x & 15;
    const int h0 = tile * 64, tid = threadIdx.x;

    #pragma unroll 8
    for (int k = 0; k < 16; ++k) {                // 256 rows x 16 float4 = 4096
        int idx = (k << 8) + tid;
        int i = idx >> 4, c4 = (idx & 15) << 2;
        *(float4*)(wl + i * 64 + c4) =
            *(const float4*)(w_t + (size_t)i * N_H + h0 + c4);
    }
    if (tid < 64) wl[256 * 64 + tid] = 0.0f;      // sentinel row
    __syncthreads();

    const int wv = __builtin_amdgcn_readfirstlane(tid >> 6);  // uniform wave id 0..3
    const int b  = (bg << 2) + wv;                // one b per wave, uniform
    const int l  = tid & 63;
    const int duo2 = (l & 31) << 1;               // float offset of h-duo
    const int half16 = (l >> 5) << 4;             // u16 units: lane-half group
    const int half32 = (l >> 5) << 4;             // u32 units: lane-half group
    const char* wlb = (const char*)wl + (duo2 << 2);  // per-lane LDS base

    // Opaque zero in a VGPR: keeps cnts loads in the vmcnt domain.
    int vzero;
    asm("v_mov_b32 %0, 0" : "=v"(vzero));

    uint32_t cW0, cW1, cW2, cW3;                  // counts (VGPR, lane-uniform)
    IdxSet W0, W1, W2, W3;

#define LOADSET(CN, S, ROW) { \
    uint32_t ro_ = (uint32_t)(ROW); \
    CN = *(cnts + ro_ + vzero); \
    const uint4* mp_ = (const uint4*)(pm + ro_ * 32u + half32); \
    S.a = mp_[0]; S.b = mp_[1]; S.c = mp_[2]; S.d = mp_[3]; }

// 4 pre-multiplied byte offsets -> 1 v_add + ds_read_b64 + pk_add per index.
// Sentinel offset 65536 = zeroed sentinel row (+0.0f).
#define GCHUNK4(G, Q) { \
    G += *(const f32x2*)(wlb + (Q).x); \
    G += *(const f32x2*)(wlb + (Q).y); \
    G += *(const f32x2*)(wlb + (Q).z); \
    G += *(const f32x2*)(wlb + (Q).w); }

// Unconditional 16-slot main gather (sentinel slots add +0.0f); chain order
// identical to all prior rounds.
#define GATHER_MAIN(G, S) { \
    GCHUNK4(G, S.a) GCHUNK4(G, S.b) GCHUNK4(G, S.c) GCHUNK4(G, S.d) }

// Rare (~7%) tail for cnt > 32: raw u16 slots, same guard ladder and
// accumulation order as before.
#define GTCHUNK(G, U0, U1) { \
    uint32_t ia0 = (U0) & 0xFFFFu; \
    uint32_t ia1 = (U0) >> 16; \
    uint32_t ia2 = (U1) & 0xFFFFu; \
    uint32_t ia3 = (U1) >> 16; \
    G += *(const f32x2*)(wl + ia0 * 64 + duo2); \
    G += *(const f32x2*)(wl + ia1 * 64 + duo2); \
    G += *(const f32x2*)(wl + ia2 * 64 + duo2); \
    G += *(const f32x2*)(wl + ia3 * 64 + duo2); }

#define GATHER_TAIL(G, CN, ROW) do { \
    uint32_t cs = __builtin_amdgcn_readfirstlane(CN); \
    if (cs > 32u) { \
        uint32_t ro_ = (uint32_t)(ROW); \
        const uint4* tp = (const uint4*)(pt + ro_ * 32u + half16); \
        uint4 T0 = tp[0], T1 = tp[1]; \
        GTCHUNK(G, T0.x, T0.y) \
        if (cs > 40u) GTCHUNK(G, T0.z, T0.w) \
        if (cs > 48u) GTCHUNK(G, T1.x, T1.y) \
        if (cs > 56u) GTCHUNK(G, T1.z, T1.w) \
    } } while (0)

// One LIF step: identical math/order to all prior rounds.
#define SCANSTEP(G, ROW) { \
    float c0 = xadd32(G.x); \
    float c1 = xadd32(G.y); \
    s0 = __builtin_fmaf(s0, 0.875f, c0); \
    s1 = __builtin_fmaf(s1, 0.875f, c1); \
    v0 = __builtin_fmaf(0.125f, s0 - v0, v0); \
    v1 = __builtin_fmaf(0.125f, s1 - v1, v1); \
    unsigned long long m0 = __ballot(v0 > 1.0f); \
    unsigned long long m1 = __ballot(v1 > 1.0f); \
    if (v0 > 1.0f) v0 = 0.0f; \
    if (v1 > 1.0f) v1 = 0.0f; \
    if (l == 0) { \
        uint2* zp = (uint2*)(zmask + (uint32_t)((ROW) * 32 + (tile << 1))); \
        *zp = make_uint2((uint32_t)m0, (uint32_t)m1); } }

    float v0 = 0, v1 = 0, s0 = 0, s1 = 0;
    LOADSET(cW0, W0, b);                         // idx(0)
    LOADSET(cW1, W1, BATCH + b);                 // idx(1)
    LOADSET(cW2, W2, 2 * BATCH + b);             // idx(2)
    LOADSET(cW3, W3, 3 * BATCH + b);             // idx(3)

    for (int t = 0; t < T_STEPS; t += 4) {
        const int rowA = t * BATCH + b;
        const int rowB = rowA + BATCH;
        const int rowC = rowB + BATCH;
        const int rowD = rowC + BATCH;

        // ---- body 1: steps t, t+1 from W0/W1; refill W0/W1 <- t+4, t+5 ----
        f32x2 ga = {0.0f, 0.0f}, gb = {0.0f, 0.0f};
        GATHER_MAIN(ga, W0);
        GATHER_MAIN(gb, W1);
        GATHER_TAIL(ga, cW0, rowA);
        GATHER_TAIL(gb, cW1, rowB);
        {
            int r4 = t + 4; if (r4 > T_STEPS - 1) r4 = T_STEPS - 1;
            int r5 = t + 5; if (r5 > T_STEPS - 1) r5 = T_STEPS - 1;
            LOADSET(cW0, W0, r4 * BATCH + b);
            LOADSET(cW1, W1, r5 * BATCH + b);
        }
        SCANSTEP(ga, rowA);
        SCANSTEP(gb, rowB);

        // ---- body 2: steps t+2, t+3 from W2/W3; refill W2/W3 <- t+6, t+7 ----
        f32x2 gc = {0.0f, 0.0f}, gd = {0.0f, 0.0f};
        GATHER_MAIN(gc, W2);
        GATHER_MAIN(gd, W3);
        GATHER_TAIL(gc, cW2, rowC);
        GATHER_TAIL(gd, cW3, rowD);
        {
            int r6 = t + 6; if (r6 > T_STEPS - 1) r6 = T_STEPS - 1;
            int r7 = t + 7; if (r7 > T_STEPS - 1) r7 = T_STEPS - 1;
            LOADSET(cW2, W2, r6 * BATCH + b);
            LOADSET(cW3, W3, r7 * BATCH + b);
        }
        SCANSTEP(gc, rowC);
        SCANSTEP(gd, rowD);
    }
#undef LOADSET
#undef GCHUNK4
#undef GATHER_MAIN
#undef GTCHUNK
#undef GATHER_TAIL
#undef SCANSTEP
}

// DPP partial-sum ladder step: returns x shifted by CTRL (invalid lanes -> 0),
// pure VALU, hazards handled by the backend (GCNDPPCombine folds the mov into
// the consuming v_add -> v_add_f32_dpp).
#define DPP_TERM(X, CTRL) \
    __int_as_float(__builtin_amdgcn_update_dpp(0, __float_as_int(X), CTRL, 0xF, 0xF, true))

// ---------------- Kernel 34: output synapse + LI scan, 8-way t-split ----------------
// Round-24: k_li is latency-bound AND grid-limited. Throughput floor ~38 us
// (LDS 1440 cyc + VALU 800 cyc per CU-iter) vs ~120 us estimated actual ->
// 3x exposed-latency slack; grid 1024 = only 4 blk/CU (16 waves/CU) while
// 18.4 KB LDS permits 8. Fix: segments of 64 t-steps (8 segs) -> grid 2048 =
// 8 blk/CU = 32 waves/CU (max occupancy), serial chain halves (32 iters).
// Per-segment math unchanged; k_fix generalizes through M^64. 4-output b128
// gather + xpick combine as verified in r9.
__global__ __launch_bounds__(256) void k_li(const uint32_t* __restrict__ zmask,
                                            const float* __restrict__ w_o,
                                            float* __restrict__ out,
                                            float2* __restrict__ svbuf) {
    extern __shared__ __align__(16) float wo4[];  // 1152 slots * 16 B = 18,432 B
    const int gb  = blockIdx.x;                   // seg(8) x bquad(32) x oct(8)
    const int seg = gb >> 8;
    const int rem = gb & 255;
    const int bq  = rem >> 3;
    const int oct = rem & 7;
    const int o0  = oct << 2;
    const int tid = threadIdx.x;

    // Stage wo4[bit][o]: bit = word*32+j -> h = ((bit>>6)<<6)+((bit&31)<<1)+((bit>>5)&1);
    // slot(bit) = bit + (bit>>3)  (16B pad every 8 slots -> bank-set spread).
    for (int lin = tid; lin < 4096; lin += 256) {
        int o = lin & 3, idx = lin >> 2;
        int h = ((idx >> 6) << 6) + ((idx & 31) << 1) + ((idx >> 5) & 1);
        wo4[((idx + (idx >> 3)) << 2) + o] = w_o[(size_t)(o0 + o) * N_H + h];
    }
    __syncthreads();

    const int b    = (bq << 2) + (tid >> 6);      // one b per wave
    const int l    = tid & 63;
    const int word = l & 31;
    const int tofs = l >> 5;                      // half A: t, half B: t+1
    const uint32_t baseoff = (uint32_t)(576 * word);   // (36*word)*16 bytes
    const char* wbase = (const char*)wo4 + baseoff;
    const int t0 = seg << 6, t1 = t0 + 64;        // 64-step segment

    float s0 = 0, s1 = 0, s2 = 0, s3 = 0;
    float v0 = 0, v1 = 0, v2 = 0, v3 = 0;

    uint32_t mcur = zmask[(uint32_t)((t0 + tofs) * BATCH + b) * 32 + word];
    for (int t = t0; t < t1; t += 2) {
        uint32_t ma = mcur;
        int tp = t + 2; if (tp >= t1) tp = t0;    // dummy prefetch on last pair
        mcur = zmask[(uint32_t)((tp + tofs) * BATCH + b) * 32 + word];

        float a0 = 0.0f, a1 = 0.0f, a2 = 0.0f, a3 = 0.0f;
        while (ma) {
            int j = __builtin_ctz(ma); ma &= ma - 1;
            const float4 wv = *(const float4*)(wbase + (((j + (j >> 3)) << 4)));
            a0 += wv.x; a1 += wv.y; a2 += wv.z; a3 += wv.w;
        }

        // 5-level DPP ladder per accumulator (4 independent chains interleave);
        // each 32-lane half reduces itself; lane 31 (and 63) hold the sums.
        a0 += DPP_TERM(a0, 0x111); a1 += DPP_TERM(a1, 0x111);
        a2 += DPP_TERM(a2, 0x111); a3 += DPP_TERM(a3, 0x111);
        a0 += DPP_TERM(a0, 0x112); a1 += DPP_TERM(a1, 0x112);
        a2 += DPP_TERM(a2, 0x112); a3 += DPP_TERM(a3, 0x112);
        a0 += DPP_TERM(a0, 0x114); a1 += DPP_TERM(a1, 0x114);
        a2 += DPP_TERM(a2, 0x114); a3 += DPP_TERM(a3, 0x114);
        a0 += DPP_TERM(a0, 0x118); a1 += DPP_TERM(a1, 0x118);
        a2 += DPP_TERM(a2, 0x118); a3 += DPP_TERM(a3, 0x118);
        a0 += DPP_TERM(a0, 0x142); a1 += DPP_TERM(a1, 0x142);
        a2 += DPP_TERM(a2, 0x142); a3 += DPP_TERM(a3, 0x142);

        // at lane 31: cA_k = a_k (own half sum), cB_k = xpick(a_k) = lane 63's
        // half-B sum, exact under either permlane operand convention.
        float b0 = xpick(a0), b1 = xpick(a1), b2 = xpick(a2), b3 = xpick(a3);

        // recurrence (meaningful at lane 31; computed everywhere, stored at 31)
        s0 = __builtin_fmaf(s0, 0.875f, a0); v0 = __builtin_fmaf(0.125f, s0 - v0, v0);
        s1 = __builtin_fmaf(s1, 0.875f, a1); v1 = __builtin_fmaf(0.125f, s1 - v1, v1);
        s2 = __builtin_fmaf(s2, 0.875f, a2); v2 = __builtin_fmaf(0.125f, s2 - v2, v2);
        s3 = __builtin_fmaf(s3, 0.875f, a3); v3 = __builtin_fmaf(0.125f, s3 - v3, v3);
        if (l == 31)
            *(float4*)(out + (size_t)(t * BATCH + b) * 32 + o0) =
                make_float4(v0, v1, v2, v3);

        s0 = __builtin_fmaf(s0, 0.875f, b0); v0 = __builtin_fmaf(0.125f, s0 - v0, v0);
        s1 = __builtin_fmaf(s1, 0.875f, b1); v1 = __builtin_fmaf(0.125f, s1 - v1, v1);
        s2 = __builtin_fmaf(s2, 0.875f, b2); v2 = __builtin_fmaf(0.125f, s2 - v2, v2);
        s3 = __builtin_fmaf(s3, 0.875f, b3); v3 = __builtin_fmaf(0.125f, s3 - v3, v3);
        if (l == 31)
            *(float4*)(out + (size_t)((t + 1) * BATCH + b) * 32 + o0) =
                make_float4(v0, v1, v2, v3);
    }
    if (l == 31) {                        // zero-run end state of this segment
        float2* sp = svbuf + ((size_t)seg * BATCH + b) * 32 + o0;
        sp[0] = make_float2(s0, v0);
        sp[1] = make_float2(s1, v1);
        sp[2] = make_float2(s2, v2);
        sp[3] = make_float2(s3, v3);
    }
}

// ---------------- Kernel F: homogeneous LI correction for segs 1..7 ----------------
// M^k on (i,v): i->a^k i ; v->a^k v + 0.125 k a^k i  (a = 0.875, equal
// eigenvalues). M^64: A64 = 0.875^64, C64 = 0.125*64*A64. True seg-s start =
// fold of prior zero-run end states through M^64 (uniform loop: t, hence seg,
// is constant per 256-thread block). svbuf is L2-resident (256 KB).
__global__ __launch_bounds__(256) void k_fix(const float2* __restrict__ svbuf,
                                             float* __restrict__ out) {
    int idx = blockIdx.x * 256 + threadIdx.x;     // 448*128*32 elements
    int o = idx & 31;
    int r = idx >> 5;
    int b = r & 127;
    int t = 64 + (r >> 7);                        // t in [64, 512)
    int seg = t >> 6;                             // 1..7
    int k = (t & 63) + 1;                         // 1..64
    const float A64 = 1.9431852e-4f;              // 0.875^64
    const float C64 = 1.5545481e-3f;              // 0.125*64*A64
    float2 S = svbuf[(size_t)b * 32 + o];         // seg-0 zero-run end state
    for (int q = 1; q < seg; ++q) {               // uniform trip count per block
        float2 z = svbuf[((size_t)q * BATCH + b) * 32 + o];
        S = make_float2(z.x + A64 * S.x, z.y + A64 * S.y + C64 * S.x);
    }
    float ak = exp2f((float)k * -0.19264508f);    // 0.875^k
    float corr = __builtin_fmaf(ak, S.y, 0.125f * (float)k * ak * S.x);
    out[(size_t)(t * BATCH + b) * 32 + o] += corr;
}

// ---------------- launch ----------------
extern "C" void kernel_launch(void* const* d_in, const int* in_sizes, int n_in,
                              void* d_out, int out_size, void* d_ws, size_t ws_size,
                              hipStream_t stream) {
    const float* spikes = (const float*)d_in[0];
    const float* w_h    = (const float*)d_in[1];
    const float* w_o    = (const float*)d_in[2];
    float* out = (float*)d_out;

    char* ws = (char*)d_ws;
    uint32_t* pm    = (uint32_t*)(ws);                 //  8,388,608
    uint16_t* pt    = (uint16_t*)(ws + 8388608);       //  4,194,304
    uint32_t* cnts  = (uint32_t*)(ws + 12582912);      //    262,144
    float*    w_t   = (float*)   (ws + 12845056);      //  1,048,576
    uint32_t* zmask = (uint32_t*)(ws + 13893632);      //  8,388,608
    float2*   svbuf = (float2*)  (ws);                 //    262,144 (reuses pm;
                                                       //    ordered after k_lif)

    const int lds12 = (256 * 64 + 64) * 4;   // 65,792 B -> 2 blocks/CU
    const int lds34 = 1152 * 16;             // 18,432 B -> 8 blocks/CU
    hipFuncSetAttribute((const void*)k_lif, hipFuncAttributeMaxDynamicSharedMemorySize, lds12);
    hipFuncSetAttribute((const void*)k_li,  hipFuncAttributeMaxDynamicSharedMemorySize, lds34);

    k_prep<<<(T_STEPS * BATCH) / 16, 256, 0, stream>>>(spikes, pm, pt, cnts);
    k_tr<<<(N_H * N_IN) / 256, 256, 0, stream>>>(w_h, w_t);
    k_lif<<<512, 256, lds12, stream>>>(pm, pt, cnts, w_t, zmask);
    k_li<<<8 * 32 * 8, 256, lds34, stream>>>(zmask, w_o, out, svbuf);
    k_fix<<<(448 * BATCH * N_OUT) / 256, 256, 0, stream>>>(svbuf, out);
}